// Round 1
// baseline (1305.742 us; speedup 1.0000x reference)
//
#include <hip/hip_runtime.h>
#include <cstdint>
#include <cstddef>

#define NEG_SLOPE 0.2f

// ---------- helpers ----------
__device__ __forceinline__ unsigned enc_f(float f) {
  unsigned u = __float_as_uint(f);
  return (u & 0x80000000u) ? ~u : (u | 0x80000000u);
}
__device__ __forceinline__ float dec_f(unsigned u) {
  unsigned b = (u & 0x80000000u) ? (u ^ 0x80000000u) : ~u;
  return __uint_as_float(b);
}

// ---------- tiny prep: V vectors for alpha computation ----------
// Vs1[k,h] = sum_c W1[k, h*128+c] * a_src1[h,c]   (64x4)
__global__ void prep_v1_kernel(const float* __restrict__ W1, const float* __restrict__ as1,
                               const float* __restrict__ ad1, float* __restrict__ Vs,
                               float* __restrict__ Vd) {
  int k = threadIdx.x >> 2, h = threadIdx.x & 3;
  const float* w = W1 + k * 512 + h * 128;
  const float* a1 = as1 + h * 128;
  const float* a2 = ad1 + h * 128;
  float s = 0.f, d = 0.f;
  for (int c = 0; c < 128; ++c) { float wv = w[c]; s += wv * a1[c]; d += wv * a2[c]; }
  Vs[k * 4 + h] = s; Vd[k * 4 + h] = d;
}

// vs2[k] = sum_c W2[k,c] * a_src2[c]   (512)
__global__ void prep_v2_kernel(const float* __restrict__ W2, const float* __restrict__ as2,
                               const float* __restrict__ ad2, float* __restrict__ vs,
                               float* __restrict__ vd) {
  int k = blockIdx.x * blockDim.x + threadIdx.x;
  if (k >= 512) return;
  const float* w = W2 + k * 256;
  float s = 0.f, d = 0.f;
  for (int c = 0; c < 256; ++c) { float wv = w[c]; s += wv * as2[c]; d += wv * ad2[c]; }
  vs[k] = s; vd[k] = d;
}

// ---------- fp32 GEMM: C[M,N] = A[M,K] @ B[K,N], row-major, N%64==0, K%16==0 ----------
__global__ __launch_bounds__(256) void gemm_f32_kernel(const float* __restrict__ A,
                                                       const float* __restrict__ B,
                                                       float* __restrict__ C,
                                                       int M, int N, int K) {
  __shared__ float As[16][68];   // transposed: As[k][m]; 68 pad -> 16B-aligned rows, 2-way max
  __shared__ float Bs[16][64];
  int tid = threadIdx.x;
  int m0 = blockIdx.x * 64, n0 = blockIdx.y * 64;
  int tx = tid & 15, ty = tid >> 4;
  int am = tid >> 2, ak = (tid & 3) * 4;
  int bk = tid >> 4, bn = (tid & 15) * 4;
  float acc[4][4] = {};
  for (int k0 = 0; k0 < K; k0 += 16) {
    float4 av = make_float4(0.f, 0.f, 0.f, 0.f);
    int arow = m0 + am;
    if (arow < M) av = *(const float4*)(A + (size_t)arow * K + k0 + ak);
    As[ak + 0][am] = av.x; As[ak + 1][am] = av.y; As[ak + 2][am] = av.z; As[ak + 3][am] = av.w;
    *(float4*)(&Bs[bk][bn]) = *(const float4*)(B + (size_t)(k0 + bk) * N + n0 + bn);
    __syncthreads();
#pragma unroll
    for (int kk = 0; kk < 16; ++kk) {
      float4 a = *(const float4*)(&As[kk][ty * 4]);
      float4 b = *(const float4*)(&Bs[kk][tx * 4]);
      acc[0][0] += a.x * b.x; acc[0][1] += a.x * b.y; acc[0][2] += a.x * b.z; acc[0][3] += a.x * b.w;
      acc[1][0] += a.y * b.x; acc[1][1] += a.y * b.y; acc[1][2] += a.y * b.z; acc[1][3] += a.y * b.w;
      acc[2][0] += a.z * b.x; acc[2][1] += a.z * b.y; acc[2][2] += a.z * b.z; acc[2][3] += a.z * b.w;
      acc[3][0] += a.w * b.x; acc[3][1] += a.w * b.y; acc[3][2] += a.w * b.z; acc[3][3] += a.w * b.w;
    }
    __syncthreads();
  }
#pragma unroll
  for (int i = 0; i < 4; ++i) {
    int row = m0 + ty * 4 + i;
    if (row < M) {
      float4 r = make_float4(acc[i][0], acc[i][1], acc[i][2], acc[i][3]);
      *(float4*)(C + (size_t)row * N + n0 + tx * 4) = r;
    }
  }
}

// ---------- per-node alpha: as[n,h] = X[n,:] . Vs[:,h] ----------
template <int H>
__global__ void alpha_nodes_kernel(const float* __restrict__ X, const float* __restrict__ Vs,
                                   const float* __restrict__ Vd, float* __restrict__ as_,
                                   float* __restrict__ ad_, int n, int K) {
  __shared__ float sVs[512];
  __shared__ float sVd[512];
  for (int i = threadIdx.x; i < K * H; i += blockDim.x) { sVs[i] = Vs[i]; sVd[i] = Vd[i]; }
  __syncthreads();
  int node = blockIdx.x * blockDim.x + threadIdx.x;
  if (node >= n) return;
  const float* xr = X + (size_t)node * K;
  float accs[H] = {}, accd[H] = {};
  for (int k = 0; k < K; k += 4) {
    float4 xv = *(const float4*)(xr + k);
#pragma unroll
    for (int h = 0; h < H; ++h) {
      accs[h] += xv.x * sVs[(k + 0) * H + h] + xv.y * sVs[(k + 1) * H + h] +
                 xv.z * sVs[(k + 2) * H + h] + xv.w * sVs[(k + 3) * H + h];
      accd[h] += xv.x * sVd[(k + 0) * H + h] + xv.y * sVd[(k + 1) * H + h] +
                 xv.z * sVd[(k + 2) * H + h] + xv.w * sVd[(k + 3) * H + h];
    }
  }
#pragma unroll
  for (int h = 0; h < H; ++h) { as_[(size_t)node * H + h] = accs[h]; ad_[(size_t)node * H + h] = accd[h]; }
}

// ---------- edge passes ----------
template <int H>
__global__ void edge_max_kernel(const int* __restrict__ ei, int E, int ntot,
                                const float* __restrict__ as_, const float* __restrict__ ad_,
                                unsigned* __restrict__ m) {
  int e = blockIdx.x * blockDim.x + threadIdx.x;
  if (e >= ntot) return;
  int s, d;
  if (e < E) { s = ei[e]; d = ei[E + e]; } else { s = d = e - E; }
#pragma unroll
  for (int h = 0; h < H; ++h) {
    float l = as_[(size_t)s * H + h] + ad_[(size_t)d * H + h];
    l = l >= 0.f ? l : NEG_SLOPE * l;
    atomicMax(&m[(size_t)d * H + h], enc_f(l));
  }
}

template <int H>
__global__ void edge_expsum_kernel(const int* __restrict__ ei, int E, int ntot,
                                   const float* __restrict__ as_, const float* __restrict__ ad_,
                                   const unsigned* __restrict__ m, float* __restrict__ ew,
                                   float* __restrict__ denom) {
  int e = blockIdx.x * blockDim.x + threadIdx.x;
  if (e >= ntot) return;
  int s, d;
  if (e < E) { s = ei[e]; d = ei[E + e]; } else { s = d = e - E; }
#pragma unroll
  for (int h = 0; h < H; ++h) {
    float l = as_[(size_t)s * H + h] + ad_[(size_t)d * H + h];
    l = l >= 0.f ? l : NEG_SLOPE * l;
    float mm = dec_f(m[(size_t)d * H + h]);
    float w = __expf(l - mm);
    ew[(size_t)e * H + h] = w;
    atomicAdd(&denom[(size_t)d * H + h], w);
  }
}

// ---------- CSR build ----------
__global__ void deg_kernel(const int* __restrict__ ei, int E, int ntot, int* __restrict__ deg) {
  int e = blockIdx.x * blockDim.x + threadIdx.x;
  if (e >= ntot) return;
  int d = (e < E) ? ei[E + e] : e - E;
  atomicAdd(&deg[d], 1);
}

__global__ void exscan_kernel(const int* __restrict__ deg, int* __restrict__ off, int n) {
  __shared__ int wsum[16];
  __shared__ int s_carry;
  int lane = threadIdx.x & 63, wid = threadIdx.x >> 6;
  if (threadIdx.x == 0) s_carry = 0;
  __syncthreads();
  for (int base = 0; base < n; base += 1024) {
    int i = base + threadIdx.x;
    int v = (i < n) ? deg[i] : 0;
    int x = v;
#pragma unroll
    for (int s = 1; s < 64; s <<= 1) {
      int t = __shfl_up(x, s, 64);
      if (lane >= s) x += t;
    }
    if (lane == 63) wsum[wid] = x;
    __syncthreads();
    if (wid == 0) {
      int w = (lane < 16) ? wsum[lane] : 0;
#pragma unroll
      for (int s = 1; s < 16; s <<= 1) {
        int t = __shfl_up(w, s, 64);
        if (lane >= s) w += t;
      }
      if (lane < 16) wsum[lane] = w;
    }
    __syncthreads();
    int wbase = (wid > 0) ? wsum[wid - 1] : 0;
    int carry = s_carry;
    if (i < n) off[i] = carry + wbase + x - v;
    __syncthreads();
    if (threadIdx.x == 1023) s_carry = carry + wsum[15];
    __syncthreads();
  }
  if (threadIdx.x == 0) off[n] = s_carry;
}

__global__ void scatter_kernel(const int* __restrict__ ei, int E, int ntot,
                               const int* __restrict__ off, int* __restrict__ cursor,
                               int* __restrict__ csr_src, int* __restrict__ csr_eid) {
  int e = blockIdx.x * blockDim.x + threadIdx.x;
  if (e >= ntot) return;
  int s, d;
  if (e < E) { s = ei[e]; d = ei[E + e]; } else { s = d = e - E; }
  int p = atomicAdd(&cursor[d], 1);
  int idx = off[d] + p;
  csr_src[idx] = s;
  csr_eid[idx] = e;
}

// ---------- aggregation: out[d,c] = sum_e alpha(e) * xw[src_e,c]  (+bias, opt ELU) ----------
__global__ void aggregate_kernel(const int* __restrict__ off, const int* __restrict__ csr_src,
                                 const int* __restrict__ csr_eid, const float* __restrict__ xw,
                                 const float* __restrict__ ew, const float* __restrict__ denom,
                                 const float* __restrict__ bias, float* __restrict__ out,
                                 int H, int C, int cph_shift, int apply_elu) {
  int d = blockIdx.x;
  int c0 = threadIdx.x * 4;
  int h = c0 >> cph_shift;
  float inv = 1.0f / denom[(size_t)d * H + h];
  float a0 = 0.f, a1 = 0.f, a2 = 0.f, a3 = 0.f;
  int beg = off[d], end = off[d + 1];
  for (int i = beg; i < end; ++i) {
    int s = csr_src[i];
    int eid = csr_eid[i];
    float a = ew[(size_t)eid * H + h] * inv;
    float4 v = *(const float4*)(xw + (size_t)s * C + c0);
    a0 += v.x * a; a1 += v.y * a; a2 += v.z * a; a3 += v.w * a;
  }
  float4 r;
  r.x = a0 + bias[c0 + 0];
  r.y = a1 + bias[c0 + 1];
  r.z = a2 + bias[c0 + 2];
  r.w = a3 + bias[c0 + 3];
  if (apply_elu) {
    r.x = r.x > 0.f ? r.x : __expf(r.x) - 1.f;
    r.y = r.y > 0.f ? r.y : __expf(r.y) - 1.f;
    r.z = r.z > 0.f ? r.z : __expf(r.z) - 1.f;
    r.w = r.w > 0.f ? r.w : __expf(r.w) - 1.f;
  }
  *(float4*)(out + (size_t)d * C + c0) = r;
}

// ---------- final mean over nodes ----------
__global__ void mean_reduce_kernel(const float* __restrict__ out2, float* __restrict__ dout, int n) {
  int col = threadIdx.x;  // 256
  float acc = 0.f;
  for (int r = blockIdx.x; r < n; r += gridDim.x) acc += out2[(size_t)r * 256 + col];
  atomicAdd(&dout[col], acc * (1.0f / (float)n));
}

__global__ void bcast_kernel(float* __restrict__ dout, int total) {
  int i = blockIdx.x * blockDim.x + threadIdx.x;
  if (i >= 256 && i < total) dout[i] = dout[i & 255];
}

// ---------- host ----------
extern "C" void kernel_launch(void* const* d_in, const int* in_sizes, int n_in,
                              void* d_out, int out_size, void* d_ws, size_t ws_size,
                              hipStream_t stream) {
  const int* ei = (const int*)d_in[0];
  const float* emb = (const float*)d_in[1];
  const float* W1 = (const float*)d_in[2];
  const float* as1w = (const float*)d_in[3];
  const float* ad1w = (const float*)d_in[4];
  const float* b1 = (const float*)d_in[5];
  const float* W2 = (const float*)d_in[6];
  const float* as2w = (const float*)d_in[7];
  const float* ad2w = (const float*)d_in[8];
  const float* b2 = (const float*)d_in[9];
  float* out = (float*)d_out;

  const int E = in_sizes[0] / 2;
  const int N = in_sizes[1] / 64;
  const int NT = E + N;

  char* ws = (char*)d_ws;
  size_t o = 0;
  auto alloc = [&](size_t bytes) { size_t r = o; o += (bytes + 255) & ~(size_t)255; return r; };
  float* bufA   = (float*)(ws + alloc((size_t)N * 512 * 4));  // xw1; reused as xw2 | out2
  float* x1     = (float*)(ws + alloc((size_t)N * 512 * 4));
  float* ew1    = (float*)(ws + alloc((size_t)NT * 4 * 4));
  float* ew2    = (float*)(ws + alloc((size_t)NT * 4));
  float* as1    = (float*)(ws + alloc((size_t)N * 4 * 4));
  float* ad1    = (float*)(ws + alloc((size_t)N * 4 * 4));
  float* as2    = (float*)(ws + alloc((size_t)N * 4));
  float* ad2    = (float*)(ws + alloc((size_t)N * 4));
  size_t zbeg = o;
  unsigned* m1  = (unsigned*)(ws + alloc((size_t)N * 4 * 4));
  float* den1   = (float*)(ws + alloc((size_t)N * 4 * 4));
  unsigned* m2  = (unsigned*)(ws + alloc((size_t)N * 4));
  float* den2   = (float*)(ws + alloc((size_t)N * 4));
  int* deg      = (int*)(ws + alloc((size_t)N * 4));
  int* cursor   = (int*)(ws + alloc((size_t)N * 4));
  size_t zend = o;
  int* off      = (int*)(ws + alloc((size_t)(N + 1) * 4));
  int* csr_src  = (int*)(ws + alloc((size_t)NT * 4));
  int* csr_eid  = (int*)(ws + alloc((size_t)NT * 4));
  float* Vs1    = (float*)(ws + alloc(64 * 4 * 4));
  float* Vd1    = (float*)(ws + alloc(64 * 4 * 4));
  float* vs2    = (float*)(ws + alloc(512 * 4));
  float* vd2    = (float*)(ws + alloc(512 * 4));
  float* xw1 = bufA;
  float* xw2 = bufA;                          // layer-2 xw reuses bufA[0 : N*256)
  float* out2 = bufA + (size_t)N * 256;       // layer-2 agg output in bufA[N*256 : N*512)

  hipMemsetAsync(ws + zbeg, 0, zend - zbeg, stream);
  hipMemsetAsync(d_out, 0, (size_t)out_size * 4, stream);

  prep_v1_kernel<<<1, 256, 0, stream>>>(W1, as1w, ad1w, Vs1, Vd1);
  prep_v2_kernel<<<1, 512, 0, stream>>>(W2, as2w, ad2w, vs2, vd2);

  dim3 g1((N + 63) / 64, 512 / 64);
  gemm_f32_kernel<<<g1, 256, 0, stream>>>(emb, W1, xw1, N, 512, 64);

  int nb = (N + 255) / 256;
  alpha_nodes_kernel<4><<<nb, 256, 0, stream>>>(emb, Vs1, Vd1, as1, ad1, N, 64);

  int eb = (NT + 255) / 256;
  edge_max_kernel<4><<<eb, 256, 0, stream>>>(ei, E, NT, as1, ad1, m1);
  edge_expsum_kernel<4><<<eb, 256, 0, stream>>>(ei, E, NT, as1, ad1, m1, ew1, den1);

  deg_kernel<<<eb, 256, 0, stream>>>(ei, E, NT, deg);
  exscan_kernel<<<1, 1024, 0, stream>>>(deg, off, N);
  scatter_kernel<<<eb, 256, 0, stream>>>(ei, E, NT, off, cursor, csr_src, csr_eid);

  aggregate_kernel<<<N, 128, 0, stream>>>(off, csr_src, csr_eid, xw1, ew1, den1, b1, x1,
                                          4, 512, 7, 1);

  dim3 g2((N + 63) / 64, 256 / 64);
  gemm_f32_kernel<<<g2, 256, 0, stream>>>(x1, W2, xw2, N, 256, 512);

  alpha_nodes_kernel<1><<<nb, 256, 0, stream>>>(x1, vs2, vd2, as2, ad2, N, 512);

  edge_max_kernel<1><<<eb, 256, 0, stream>>>(ei, E, NT, as2, ad2, m2);
  edge_expsum_kernel<1><<<eb, 256, 0, stream>>>(ei, E, NT, as2, ad2, m2, ew2, den2);

  aggregate_kernel<<<N, 64, 0, stream>>>(off, csr_src, csr_eid, xw2, ew2, den2, b2, out2,
                                         1, 256, 8, 0);

  mean_reduce_kernel<<<256, 256, 0, stream>>>(out2, out, N);
  if (out_size > 256) {
    bcast_kernel<<<(out_size + 255) / 256, 256, 0, stream>>>(out, out_size);
  }
}

// Round 2
// 735.461 us; speedup vs baseline: 1.7754x; 1.7754x over previous
//
#include <hip/hip_runtime.h>
#include <cstdint>
#include <cstddef>

#define NEG_SLOPE 0.2f

typedef __bf16 bf16x8 __attribute__((ext_vector_type(8)));
typedef __bf16 bf16x4 __attribute__((ext_vector_type(4)));
typedef float f32x4 __attribute__((ext_vector_type(4)));

// ---------- tiny prep: V vectors for alpha computation ----------
// Vs1[k,h] = sum_c W1[k, h*128+c] * a_src1[h,c]   (64x4)
__global__ void prep_v1_kernel(const float* __restrict__ W1, const float* __restrict__ as1,
                               const float* __restrict__ ad1, float* __restrict__ Vs,
                               float* __restrict__ Vd) {
  int k = threadIdx.x >> 2, h = threadIdx.x & 3;
  const float* w = W1 + k * 512 + h * 128;
  const float* a1 = as1 + h * 128;
  const float* a2 = ad1 + h * 128;
  float s = 0.f, d = 0.f;
  for (int c = 0; c < 128; ++c) { float wv = w[c]; s += wv * a1[c]; d += wv * a2[c]; }
  Vs[k * 4 + h] = s; Vd[k * 4 + h] = d;
}

// vs2[k] = sum_c W2[k,c] * a_src2[c]   (512)
__global__ void prep_v2_kernel(const float* __restrict__ W2, const float* __restrict__ as2,
                               const float* __restrict__ ad2, float* __restrict__ vs,
                               float* __restrict__ vd) {
  int k = blockIdx.x * blockDim.x + threadIdx.x;
  if (k >= 512) return;
  const float* w = W2 + k * 256;
  float s = 0.f, d = 0.f;
  for (int c = 0; c < 256; ++c) { float wv = w[c]; s += wv * as2[c]; d += wv * ad2[c]; }
  vs[k] = s; vd[k] = d;
}

// ---------- dtype conversion ----------
__global__ void f32_to_bf16_kernel(const float* __restrict__ in, __bf16* __restrict__ out,
                                   size_t n4) {
  size_t i = ((size_t)blockIdx.x * blockDim.x + threadIdx.x);
  if (i >= n4) return;
  float4 v = *(const float4*)(in + i * 4);
  bf16x4 o;
  o[0] = (__bf16)v.x; o[1] = (__bf16)v.y; o[2] = (__bf16)v.z; o[3] = (__bf16)v.w;
  *(bf16x4*)(out + i * 4) = o;
}

// out[n*K+k] = bf16(in[k*N+n])  -- W [K,N] fp32 -> WT [N,K] bf16
__global__ void transpose_bf16_kernel(const float* __restrict__ in, __bf16* __restrict__ out,
                                      int K, int N) {
  int idx = blockIdx.x * blockDim.x + threadIdx.x;
  if (idx >= K * N) return;
  int n = idx / K, k = idx - n * K;
  out[idx] = (__bf16)in[(size_t)k * N + n];
}

// ---------- bf16 MFMA GEMM: C[M,N] = A[M,K] @ BT[N,K]^T ----------
// 128x128 block tile, BK=32, 4 waves (2x2), per-wave 64x64 via 4x4 frags of 16x16x32.
__global__ __launch_bounds__(256) void gemm_bf16_kernel(const __bf16* __restrict__ A,
                                                        const __bf16* __restrict__ BT,
                                                        __bf16* __restrict__ C,
                                                        int M, int N, int K) {
  __shared__ __bf16 Asl[128 * 32];
  __shared__ __bf16 Bsl[128 * 32];
  int tid = threadIdx.x;
  int m0 = blockIdx.x * 128, n0 = blockIdx.y * 128;
  int wave = tid >> 6, lane = tid & 63;
  int wm = (wave >> 1) * 64, wn = (wave & 1) * 64;
  int l15 = lane & 15, kg = lane >> 4;
  f32x4 acc[4][4] = {};
  for (int k0 = 0; k0 < K; k0 += 32) {
    // stage A and BT tiles: 128 rows x 32 k (64B/row = 4 chunks of 16B)
#pragma unroll
    for (int i = 0; i < 2; ++i) {
      int c = tid + i * 256;              // 0..511
      int row = c >> 2, off = (c & 3) * 8;
      bf16x8 va = {};
      int gr = m0 + row;
      if (gr < M) va = *(const bf16x8*)(A + (size_t)gr * K + k0 + off);
      *(bf16x8*)(&Asl[row * 32 + off]) = va;
      bf16x8 vb = *(const bf16x8*)(BT + (size_t)(n0 + row) * K + k0 + off);
      *(bf16x8*)(&Bsl[row * 32 + off]) = vb;
    }
    __syncthreads();
    bf16x8 af[4], bfr[4];
#pragma unroll
    for (int f = 0; f < 4; ++f) {
      af[f]  = *(const bf16x8*)(&Asl[(wm + f * 16 + l15) * 32 + kg * 8]);
      bfr[f] = *(const bf16x8*)(&Bsl[(wn + f * 16 + l15) * 32 + kg * 8]);
    }
#pragma unroll
    for (int i = 0; i < 4; ++i)
#pragma unroll
      for (int j = 0; j < 4; ++j)
        acc[i][j] = __builtin_amdgcn_mfma_f32_16x16x32_bf16(af[i], bfr[j], acc[i][j], 0, 0, 0);
    __syncthreads();
  }
#pragma unroll
  for (int i = 0; i < 4; ++i)
#pragma unroll
    for (int j = 0; j < 4; ++j)
#pragma unroll
      for (int r = 0; r < 4; ++r) {
        int row = m0 + wm + i * 16 + kg * 4 + r;
        int col = n0 + wn + j * 16 + l15;
        if (row < M) C[(size_t)row * N + col] = (__bf16)acc[i][j][r];
      }
}

// ---------- per-node alpha: fp32 X (layer 1) ----------
template <int H>
__global__ void alpha_nodes_kernel(const float* __restrict__ X, const float* __restrict__ Vs,
                                   const float* __restrict__ Vd, float* __restrict__ as_,
                                   float* __restrict__ ad_, int n, int K) {
  __shared__ float sVs[512];
  __shared__ float sVd[512];
  for (int i = threadIdx.x; i < K * H; i += blockDim.x) { sVs[i] = Vs[i]; sVd[i] = Vd[i]; }
  __syncthreads();
  int node = blockIdx.x * blockDim.x + threadIdx.x;
  if (node >= n) return;
  const float* xr = X + (size_t)node * K;
  float accs[H] = {}, accd[H] = {};
  for (int k = 0; k < K; k += 4) {
    float4 xv = *(const float4*)(xr + k);
#pragma unroll
    for (int h = 0; h < H; ++h) {
      accs[h] += xv.x * sVs[(k + 0) * H + h] + xv.y * sVs[(k + 1) * H + h] +
                 xv.z * sVs[(k + 2) * H + h] + xv.w * sVs[(k + 3) * H + h];
      accd[h] += xv.x * sVd[(k + 0) * H + h] + xv.y * sVd[(k + 1) * H + h] +
                 xv.z * sVd[(k + 2) * H + h] + xv.w * sVd[(k + 3) * H + h];
    }
  }
#pragma unroll
  for (int h = 0; h < H; ++h) { as_[(size_t)node * H + h] = accs[h]; ad_[(size_t)node * H + h] = accd[h]; }
}

// ---------- per-node alpha: bf16 X (layer 2, H=1) ----------
__global__ void alpha_nodes_bf16_kernel(const __bf16* __restrict__ X, const float* __restrict__ vs,
                                        const float* __restrict__ vd, float* __restrict__ as_,
                                        float* __restrict__ ad_, int n, int K) {
  __shared__ float sVs[512];
  __shared__ float sVd[512];
  for (int i = threadIdx.x; i < K; i += blockDim.x) { sVs[i] = vs[i]; sVd[i] = vd[i]; }
  __syncthreads();
  int node = blockIdx.x * blockDim.x + threadIdx.x;
  if (node >= n) return;
  const __bf16* xr = X + (size_t)node * K;
  float s = 0.f, d = 0.f;
  for (int k = 0; k < K; k += 8) {
    bf16x8 v = *(const bf16x8*)(xr + k);
#pragma unroll
    for (int j = 0; j < 8; ++j) {
      float f = (float)v[j];
      s += f * sVs[k + j];
      d += f * sVd[k + j];
    }
  }
  as_[node] = s; ad_[node] = d;
}

// ---------- single edge pass: exp(leaky_relu(logit)) + denom (+deg for CSR) ----------
template <int H>
__global__ void edge_expsum_kernel(const int* __restrict__ ei, int E, int ntot,
                                   const float* __restrict__ as_, const float* __restrict__ ad_,
                                   float* __restrict__ ew, float* __restrict__ denom,
                                   int* __restrict__ deg) {
  int e = blockIdx.x * blockDim.x + threadIdx.x;
  if (e >= ntot) return;
  int s, d;
  if (e < E) { s = ei[e]; d = ei[E + e]; } else { s = d = e - E; }
  if (deg) atomicAdd(&deg[d], 1);
#pragma unroll
  for (int h = 0; h < H; ++h) {
    float l = as_[(size_t)s * H + h] + ad_[(size_t)d * H + h];
    l = l >= 0.f ? l : NEG_SLOPE * l;
    float w = __expf(l);   // no max-shift: logits O(10), fp32 exp safe; softmax shift-invariant
    ew[(size_t)e * H + h] = w;
    atomicAdd(&denom[(size_t)d * H + h], w);
  }
}

// ---------- CSR build ----------
__global__ void exscan_kernel(const int* __restrict__ deg, int* __restrict__ off, int n) {
  __shared__ int wsum[16];
  __shared__ int s_carry;
  int lane = threadIdx.x & 63, wid = threadIdx.x >> 6;
  if (threadIdx.x == 0) s_carry = 0;
  __syncthreads();
  for (int base = 0; base < n; base += 1024) {
    int i = base + threadIdx.x;
    int v = (i < n) ? deg[i] : 0;
    int x = v;
#pragma unroll
    for (int s = 1; s < 64; s <<= 1) {
      int t = __shfl_up(x, s, 64);
      if (lane >= s) x += t;
    }
    if (lane == 63) wsum[wid] = x;
    __syncthreads();
    if (wid == 0) {
      int w = (lane < 16) ? wsum[lane] : 0;
#pragma unroll
      for (int s = 1; s < 16; s <<= 1) {
        int t = __shfl_up(w, s, 64);
        if (lane >= s) w += t;
      }
      if (lane < 16) wsum[lane] = w;
    }
    __syncthreads();
    int wbase = (wid > 0) ? wsum[wid - 1] : 0;
    int carry = s_carry;
    if (i < n) off[i] = carry + wbase + x - v;
    __syncthreads();
    if (threadIdx.x == 1023) s_carry = carry + wsum[15];
    __syncthreads();
  }
  if (threadIdx.x == 0) off[n] = s_carry;
}

__global__ void scatter_kernel(const int* __restrict__ ei, int E, int ntot,
                               const int* __restrict__ off, int* __restrict__ cursor,
                               int* __restrict__ csr_src, int* __restrict__ csr_eid) {
  int e = blockIdx.x * blockDim.x + threadIdx.x;
  if (e >= ntot) return;
  int s, d;
  if (e < E) { s = ei[e]; d = ei[E + e]; } else { s = d = e - E; }
  int p = atomicAdd(&cursor[d], 1);
  int idx = off[d] + p;
  csr_src[idx] = s;
  csr_eid[idx] = e;
}

// ---------- aggregation over bf16 gather table ----------
// out[d,c] = sum_e alpha(e) * xw[src_e,c] + bias; optional ELU; bf16 or fp32 output
__global__ void aggregate_bf16_kernel(const int* __restrict__ off, const int* __restrict__ csr_src,
                                      const int* __restrict__ csr_eid, const __bf16* __restrict__ xw,
                                      const float* __restrict__ ew, const float* __restrict__ denom,
                                      const float* __restrict__ bias, __bf16* __restrict__ out_bf,
                                      float* __restrict__ out_f, int H, int C, int cph_shift,
                                      int apply_elu) {
  int d = blockIdx.x;
  int c0 = threadIdx.x * 4;
  int h = c0 >> cph_shift;
  float inv = 1.0f / denom[(size_t)d * H + h];
  float a0 = 0.f, a1 = 0.f, a2 = 0.f, a3 = 0.f;
  int beg = off[d], end = off[d + 1];
  for (int i = beg; i < end; ++i) {
    int s = csr_src[i];
    int eid = csr_eid[i];
    float a = ew[(size_t)eid * H + h] * inv;
    bf16x4 v = *(const bf16x4*)(xw + (size_t)s * C + c0);
    a0 += (float)v[0] * a; a1 += (float)v[1] * a; a2 += (float)v[2] * a; a3 += (float)v[3] * a;
  }
  a0 += bias[c0 + 0]; a1 += bias[c0 + 1]; a2 += bias[c0 + 2]; a3 += bias[c0 + 3];
  if (apply_elu) {
    a0 = a0 > 0.f ? a0 : __expf(a0) - 1.f;
    a1 = a1 > 0.f ? a1 : __expf(a1) - 1.f;
    a2 = a2 > 0.f ? a2 : __expf(a2) - 1.f;
    a3 = a3 > 0.f ? a3 : __expf(a3) - 1.f;
  }
  if (out_bf) {
    bf16x4 r;
    r[0] = (__bf16)a0; r[1] = (__bf16)a1; r[2] = (__bf16)a2; r[3] = (__bf16)a3;
    *(bf16x4*)(out_bf + (size_t)d * C + c0) = r;
  } else {
    float4 r = make_float4(a0, a1, a2, a3);
    *(float4*)(out_f + (size_t)d * C + c0) = r;
  }
}

// ---------- final mean over nodes ----------
__global__ void mean_reduce_kernel(const float* __restrict__ out2, float* __restrict__ dout, int n) {
  int col = threadIdx.x;  // 256
  float acc = 0.f;
  for (int r = blockIdx.x; r < n; r += gridDim.x) acc += out2[(size_t)r * 256 + col];
  atomicAdd(&dout[col], acc * (1.0f / (float)n));
}

__global__ void bcast_kernel(float* __restrict__ dout, int total) {
  int i = blockIdx.x * blockDim.x + threadIdx.x;
  if (i >= 256 && i < total) dout[i] = dout[i & 255];
}

// ---------- host ----------
extern "C" void kernel_launch(void* const* d_in, const int* in_sizes, int n_in,
                              void* d_out, int out_size, void* d_ws, size_t ws_size,
                              hipStream_t stream) {
  const int* ei = (const int*)d_in[0];
  const float* emb = (const float*)d_in[1];
  const float* W1 = (const float*)d_in[2];
  const float* as1w = (const float*)d_in[3];
  const float* ad1w = (const float*)d_in[4];
  const float* b1 = (const float*)d_in[5];
  const float* W2 = (const float*)d_in[6];
  const float* as2w = (const float*)d_in[7];
  const float* ad2w = (const float*)d_in[8];
  const float* b2 = (const float*)d_in[9];
  float* out = (float*)d_out;

  const int E = in_sizes[0] / 2;
  const int N = in_sizes[1] / 64;
  const int NT = E + N;

  char* ws = (char*)d_ws;
  size_t o = 0;
  auto alloc = [&](size_t bytes) { size_t r = o; o += (bytes + 255) & ~(size_t)255; return r; };
  __bf16* xw1   = (__bf16*)(ws + alloc((size_t)N * 512 * 2));
  __bf16* x1    = (__bf16*)(ws + alloc((size_t)N * 512 * 2));
  __bf16* xw2   = (__bf16*)(ws + alloc((size_t)N * 256 * 2));
  float* out2   = (float*)(ws + alloc((size_t)N * 256 * 4));
  __bf16* embb  = (__bf16*)(ws + alloc((size_t)N * 64 * 2));
  __bf16* W1T   = (__bf16*)(ws + alloc((size_t)512 * 64 * 2));
  __bf16* W2T   = (__bf16*)(ws + alloc((size_t)256 * 512 * 2));
  float* ew1    = (float*)(ws + alloc((size_t)NT * 4 * 4));
  float* ew2    = (float*)(ws + alloc((size_t)NT * 4));
  float* as1    = (float*)(ws + alloc((size_t)N * 4 * 4));
  float* ad1    = (float*)(ws + alloc((size_t)N * 4 * 4));
  float* as2    = (float*)(ws + alloc((size_t)N * 4));
  float* ad2    = (float*)(ws + alloc((size_t)N * 4));
  size_t zbeg = o;
  float* den1   = (float*)(ws + alloc((size_t)N * 4 * 4));
  float* den2   = (float*)(ws + alloc((size_t)N * 4));
  int* deg      = (int*)(ws + alloc((size_t)N * 4));
  int* cursor   = (int*)(ws + alloc((size_t)N * 4));
  size_t zend = o;
  int* off      = (int*)(ws + alloc((size_t)(N + 1) * 4));
  int* csr_src  = (int*)(ws + alloc((size_t)NT * 4));
  int* csr_eid  = (int*)(ws + alloc((size_t)NT * 4));
  float* Vs1    = (float*)(ws + alloc(64 * 4 * 4));
  float* Vd1    = (float*)(ws + alloc(64 * 4 * 4));
  float* vs2    = (float*)(ws + alloc(512 * 4));
  float* vd2    = (float*)(ws + alloc(512 * 4));

  hipMemsetAsync(ws + zbeg, 0, zend - zbeg, stream);
  hipMemsetAsync(d_out, 0, (size_t)out_size * 4, stream);

  // prep: alpha vectors, bf16 conversions, weight transposes
  prep_v1_kernel<<<1, 256, 0, stream>>>(W1, as1w, ad1w, Vs1, Vd1);
  prep_v2_kernel<<<1, 512, 0, stream>>>(W2, as2w, ad2w, vs2, vd2);
  f32_to_bf16_kernel<<<(N * 64 / 4 + 255) / 256, 256, 0, stream>>>(emb, embb, (size_t)N * 64 / 4);
  transpose_bf16_kernel<<<(64 * 512 + 255) / 256, 256, 0, stream>>>(W1, W1T, 64, 512);
  transpose_bf16_kernel<<<(512 * 256 + 255) / 256, 256, 0, stream>>>(W2, W2T, 512, 256);

  // layer 1 GEMM: xw1[N,512] = embb[N,64] @ W1T[512,64]^T
  dim3 g1((N + 127) / 128, 512 / 128);
  gemm_bf16_kernel<<<g1, 256, 0, stream>>>(embb, W1T, xw1, N, 512, 64);

  int nb = (N + 255) / 256;
  alpha_nodes_kernel<4><<<nb, 256, 0, stream>>>(emb, Vs1, Vd1, as1, ad1, N, 64);

  int eb = (NT + 255) / 256;
  edge_expsum_kernel<4><<<eb, 256, 0, stream>>>(ei, E, NT, as1, ad1, ew1, den1, deg);

  exscan_kernel<<<1, 1024, 0, stream>>>(deg, off, N);
  scatter_kernel<<<eb, 256, 0, stream>>>(ei, E, NT, off, cursor, csr_src, csr_eid);

  aggregate_bf16_kernel<<<N, 128, 0, stream>>>(off, csr_src, csr_eid, xw1, ew1, den1, b1,
                                               x1, nullptr, 4, 512, 7, 1);

  // layer 2 GEMM: xw2[N,256] = x1[N,512] @ W2T[256,512]^T
  dim3 g2((N + 127) / 128, 256 / 128);
  gemm_bf16_kernel<<<g2, 256, 0, stream>>>(x1, W2T, xw2, N, 256, 512);

  alpha_nodes_bf16_kernel<<<nb, 256, 0, stream>>>(x1, vs2, vd2, as2, ad2, N, 512);

  edge_expsum_kernel<1><<<eb, 256, 0, stream>>>(ei, E, NT, as2, ad2, ew2, den2, nullptr);

  aggregate_bf16_kernel<<<N, 64, 0, stream>>>(off, csr_src, csr_eid, xw2, ew2, den2, b2,
                                              nullptr, out2, 1, 256, 8, 0);

  mean_reduce_kernel<<<256, 256, 0, stream>>>(out2, out, N);
  if (out_size > 256) {
    bcast_kernel<<<(out_size + 255) / 256, 256, 0, stream>>>(out, out_size);
  }
}

// Round 3
// 486.788 us; speedup vs baseline: 2.6824x; 1.5108x over previous
//
#include <hip/hip_runtime.h>
#include <cstdint>
#include <cstddef>

#define NEG_SLOPE 0.2f

typedef __bf16 bf16x8 __attribute__((ext_vector_type(8)));
typedef __bf16 bf16x4 __attribute__((ext_vector_type(4)));
typedef float f32x4 __attribute__((ext_vector_type(4)));

// ---------- tiny prep: V vectors for alpha computation ----------
// Vs1[k,h] = sum_c W1[k, h*128+c] * a_src1[h,c]   (64x4)
__global__ void prep_v1_kernel(const float* __restrict__ W1, const float* __restrict__ as1,
                               const float* __restrict__ ad1, float* __restrict__ Vs,
                               float* __restrict__ Vd) {
  int k = threadIdx.x >> 2, h = threadIdx.x & 3;
  const float* w = W1 + k * 512 + h * 128;
  const float* a1 = as1 + h * 128;
  const float* a2 = ad1 + h * 128;
  float s = 0.f, d = 0.f;
  for (int c = 0; c < 128; ++c) { float wv = w[c]; s += wv * a1[c]; d += wv * a2[c]; }
  Vs[k * 4 + h] = s; Vd[k * 4 + h] = d;
}

// vs2[k] = sum_c W2[k,c] * a_src2[c]   (512)
__global__ void prep_v2_kernel(const float* __restrict__ W2, const float* __restrict__ as2,
                               const float* __restrict__ ad2, float* __restrict__ vs,
                               float* __restrict__ vd) {
  int k = blockIdx.x * blockDim.x + threadIdx.x;
  if (k >= 512) return;
  const float* w = W2 + k * 256;
  float s = 0.f, d = 0.f;
  for (int c = 0; c < 256; ++c) { float wv = w[c]; s += wv * as2[c]; d += wv * ad2[c]; }
  vs[k] = s; vd[k] = d;
}

// ---------- dtype conversion ----------
__global__ void f32_to_bf16_kernel(const float* __restrict__ in, __bf16* __restrict__ out,
                                   size_t n4) {
  size_t i = ((size_t)blockIdx.x * blockDim.x + threadIdx.x);
  if (i >= n4) return;
  float4 v = *(const float4*)(in + i * 4);
  bf16x4 o;
  o[0] = (__bf16)v.x; o[1] = (__bf16)v.y; o[2] = (__bf16)v.z; o[3] = (__bf16)v.w;
  *(bf16x4*)(out + i * 4) = o;
}

// out[n*K+k] = bf16(in[k*N+n])  -- W [K,N] fp32 -> WT [N,K] bf16
__global__ void transpose_bf16_kernel(const float* __restrict__ in, __bf16* __restrict__ out,
                                      int K, int N) {
  int idx = blockIdx.x * blockDim.x + threadIdx.x;
  if (idx >= K * N) return;
  int n = idx / K, k = idx - n * K;
  out[idx] = (__bf16)in[(size_t)k * N + n];
}

// ---------- bf16 MFMA GEMM: C[M,N] = A[M,K] @ BT[N,K]^T ----------
// 128x128 block tile, BK=32, 4 waves (2x2), per-wave 64x64 via 4x4 frags of 16x16x32.
__global__ __launch_bounds__(256) void gemm_bf16_kernel(const __bf16* __restrict__ A,
                                                        const __bf16* __restrict__ BT,
                                                        __bf16* __restrict__ C,
                                                        int M, int N, int K) {
  __shared__ __bf16 Asl[128 * 32];
  __shared__ __bf16 Bsl[128 * 32];
  int tid = threadIdx.x;
  int m0 = blockIdx.x * 128, n0 = blockIdx.y * 128;
  int wave = tid >> 6, lane = tid & 63;
  int wm = (wave >> 1) * 64, wn = (wave & 1) * 64;
  int l15 = lane & 15, kg = lane >> 4;
  f32x4 acc[4][4] = {};
  for (int k0 = 0; k0 < K; k0 += 32) {
#pragma unroll
    for (int i = 0; i < 2; ++i) {
      int c = tid + i * 256;              // 0..511
      int row = c >> 2, off = (c & 3) * 8;
      bf16x8 va = {};
      int gr = m0 + row;
      if (gr < M) va = *(const bf16x8*)(A + (size_t)gr * K + k0 + off);
      *(bf16x8*)(&Asl[row * 32 + off]) = va;
      bf16x8 vb = *(const bf16x8*)(BT + (size_t)(n0 + row) * K + k0 + off);
      *(bf16x8*)(&Bsl[row * 32 + off]) = vb;
    }
    __syncthreads();
    bf16x8 af[4], bfr[4];
#pragma unroll
    for (int f = 0; f < 4; ++f) {
      af[f]  = *(const bf16x8*)(&Asl[(wm + f * 16 + l15) * 32 + kg * 8]);
      bfr[f] = *(const bf16x8*)(&Bsl[(wn + f * 16 + l15) * 32 + kg * 8]);
    }
#pragma unroll
    for (int i = 0; i < 4; ++i)
#pragma unroll
      for (int j = 0; j < 4; ++j)
        acc[i][j] = __builtin_amdgcn_mfma_f32_16x16x32_bf16(af[i], bfr[j], acc[i][j], 0, 0, 0);
    __syncthreads();
  }
#pragma unroll
  for (int i = 0; i < 4; ++i)
#pragma unroll
    for (int j = 0; j < 4; ++j)
#pragma unroll
      for (int r = 0; r < 4; ++r) {
        int row = m0 + wm + i * 16 + kg * 4 + r;
        int col = n0 + wn + j * 16 + l15;
        if (row < M) C[(size_t)row * N + col] = (__bf16)acc[i][j][r];
      }
}

// ---------- per-node alpha: fp32 X (layer 1) ----------
template <int H>
__global__ void alpha_nodes_kernel(const float* __restrict__ X, const float* __restrict__ Vs,
                                   const float* __restrict__ Vd, float* __restrict__ as_,
                                   float* __restrict__ ad_, int n, int K) {
  __shared__ float sVs[512];
  __shared__ float sVd[512];
  for (int i = threadIdx.x; i < K * H; i += blockDim.x) { sVs[i] = Vs[i]; sVd[i] = Vd[i]; }
  __syncthreads();
  int node = blockIdx.x * blockDim.x + threadIdx.x;
  if (node >= n) return;
  const float* xr = X + (size_t)node * K;
  float accs[H] = {}, accd[H] = {};
  for (int k = 0; k < K; k += 4) {
    float4 xv = *(const float4*)(xr + k);
#pragma unroll
    for (int h = 0; h < H; ++h) {
      accs[h] += xv.x * sVs[(k + 0) * H + h] + xv.y * sVs[(k + 1) * H + h] +
                 xv.z * sVs[(k + 2) * H + h] + xv.w * sVs[(k + 3) * H + h];
      accd[h] += xv.x * sVd[(k + 0) * H + h] + xv.y * sVd[(k + 1) * H + h] +
                 xv.z * sVd[(k + 2) * H + h] + xv.w * sVd[(k + 3) * H + h];
    }
  }
#pragma unroll
  for (int h = 0; h < H; ++h) { as_[(size_t)node * H + h] = accs[h]; ad_[(size_t)node * H + h] = accd[h]; }
}

// ---------- per-node alpha: bf16 X (layer 2, H=1) ----------
__global__ void alpha_nodes_bf16_kernel(const __bf16* __restrict__ X, const float* __restrict__ vs,
                                        const float* __restrict__ vd, float* __restrict__ as_,
                                        float* __restrict__ ad_, int n, int K) {
  __shared__ float sVs[512];
  __shared__ float sVd[512];
  for (int i = threadIdx.x; i < K; i += blockDim.x) { sVs[i] = vs[i]; sVd[i] = vd[i]; }
  __syncthreads();
  int node = blockIdx.x * blockDim.x + threadIdx.x;
  if (node >= n) return;
  const __bf16* xr = X + (size_t)node * K;
  float s = 0.f, d = 0.f;
  for (int k = 0; k < K; k += 8) {
    bf16x8 v = *(const bf16x8*)(xr + k);
#pragma unroll
    for (int j = 0; j < 8; ++j) {
      float f = (float)v[j];
      s += f * sVs[k + j];
      d += f * sVd[k + j];
    }
  }
  as_[node] = s; ad_[node] = d;
}

// ---------- CSR build ----------
__global__ void deg_kernel(const int* __restrict__ ei, int E, int ntot, int* __restrict__ deg) {
  int e = blockIdx.x * blockDim.x + threadIdx.x;
  if (e >= ntot) return;
  int d = (e < E) ? ei[E + e] : e - E;
  atomicAdd(&deg[d], 1);
}

__global__ void exscan_kernel(const int* __restrict__ deg, int* __restrict__ off, int n) {
  __shared__ int wsum[16];
  __shared__ int s_carry;
  int lane = threadIdx.x & 63, wid = threadIdx.x >> 6;
  if (threadIdx.x == 0) s_carry = 0;
  __syncthreads();
  for (int base = 0; base < n; base += 1024) {
    int i = base + threadIdx.x;
    int v = (i < n) ? deg[i] : 0;
    int x = v;
#pragma unroll
    for (int s = 1; s < 64; s <<= 1) {
      int t = __shfl_up(x, s, 64);
      if (lane >= s) x += t;
    }
    if (lane == 63) wsum[wid] = x;
    __syncthreads();
    if (wid == 0) {
      int w = (lane < 16) ? wsum[lane] : 0;
#pragma unroll
      for (int s = 1; s < 16; s <<= 1) {
        int t = __shfl_up(w, s, 64);
        if (lane >= s) w += t;
      }
      if (lane < 16) wsum[lane] = w;
    }
    __syncthreads();
    int wbase = (wid > 0) ? wsum[wid - 1] : 0;
    int carry = s_carry;
    if (i < n) off[i] = carry + wbase + x - v;
    __syncthreads();
    if (threadIdx.x == 1023) s_carry = carry + wsum[15];
    __syncthreads();
  }
  if (threadIdx.x == 0) off[n] = s_carry;
}

__global__ void scatter_kernel(const int* __restrict__ ei, int E, int ntot,
                               const int* __restrict__ off, int* __restrict__ cursor,
                               int* __restrict__ csr_src) {
  int e = blockIdx.x * blockDim.x + threadIdx.x;
  if (e >= ntot) return;
  int s, d;
  if (e < E) { s = ei[e]; d = ei[E + e]; } else { s = d = e - E; }
  int p = atomicAdd(&cursor[d], 1);
  csr_src[off[d] + p] = s;
}

// ---------- fused aggregation + softmax ----------
// out[d,c] = (sum_e w_e * xw[src_e,c]) / (sum_e w_e) + bias;  w_e = exp(leaky(as[s]+ad[d]))
// optional ELU; bf16 or fp32 output
__global__ void aggregate_fused_kernel(const int* __restrict__ off, const int* __restrict__ csr_src,
                                       const __bf16* __restrict__ xw,
                                       const float* __restrict__ as_, const float* __restrict__ ad_,
                                       const float* __restrict__ bias, __bf16* __restrict__ out_bf,
                                       float* __restrict__ out_f, int H, int C, int cph_shift,
                                       int apply_elu) {
  int d = blockIdx.x;
  int c0 = threadIdx.x * 4;
  int h = c0 >> cph_shift;
  float adv = ad_[(size_t)d * H + h];
  float a0 = 0.f, a1 = 0.f, a2 = 0.f, a3 = 0.f, wsum = 0.f;
  int beg = off[d], end = off[d + 1];
#pragma unroll 4
  for (int i = beg; i < end; ++i) {
    int s = csr_src[i];
    float l = as_[(size_t)s * H + h] + adv;
    l = l >= 0.f ? l : NEG_SLOPE * l;
    float w = __expf(l);   // no max-shift: logits small, fp32 exp safe; softmax shift-invariant
    wsum += w;
    bf16x4 v = *(const bf16x4*)(xw + (size_t)s * C + c0);
    a0 += (float)v[0] * w; a1 += (float)v[1] * w; a2 += (float)v[2] * w; a3 += (float)v[3] * w;
  }
  float inv = 1.0f / wsum;
  a0 = a0 * inv + bias[c0 + 0];
  a1 = a1 * inv + bias[c0 + 1];
  a2 = a2 * inv + bias[c0 + 2];
  a3 = a3 * inv + bias[c0 + 3];
  if (apply_elu) {
    a0 = a0 > 0.f ? a0 : __expf(a0) - 1.f;
    a1 = a1 > 0.f ? a1 : __expf(a1) - 1.f;
    a2 = a2 > 0.f ? a2 : __expf(a2) - 1.f;
    a3 = a3 > 0.f ? a3 : __expf(a3) - 1.f;
  }
  if (out_bf) {
    bf16x4 r;
    r[0] = (__bf16)a0; r[1] = (__bf16)a1; r[2] = (__bf16)a2; r[3] = (__bf16)a3;
    *(bf16x4*)(out_bf + (size_t)d * C + c0) = r;
  } else {
    float4 r = make_float4(a0, a1, a2, a3);
    *(float4*)(out_f + (size_t)d * C + c0) = r;
  }
}

// ---------- final mean over nodes ----------
__global__ void mean_reduce_kernel(const float* __restrict__ out2, float* __restrict__ dout, int n) {
  int col = threadIdx.x;  // 256
  float acc = 0.f;
  for (int r = blockIdx.x; r < n; r += gridDim.x) acc += out2[(size_t)r * 256 + col];
  atomicAdd(&dout[col], acc * (1.0f / (float)n));
}

__global__ void bcast_kernel(float* __restrict__ dout, int total) {
  int i = blockIdx.x * blockDim.x + threadIdx.x;
  if (i >= 256 && i < total) dout[i] = dout[i & 255];
}

// ---------- host ----------
extern "C" void kernel_launch(void* const* d_in, const int* in_sizes, int n_in,
                              void* d_out, int out_size, void* d_ws, size_t ws_size,
                              hipStream_t stream) {
  const int* ei = (const int*)d_in[0];
  const float* emb = (const float*)d_in[1];
  const float* W1 = (const float*)d_in[2];
  const float* as1w = (const float*)d_in[3];
  const float* ad1w = (const float*)d_in[4];
  const float* b1 = (const float*)d_in[5];
  const float* W2 = (const float*)d_in[6];
  const float* as2w = (const float*)d_in[7];
  const float* ad2w = (const float*)d_in[8];
  const float* b2 = (const float*)d_in[9];
  float* out = (float*)d_out;

  const int E = in_sizes[0] / 2;
  const int N = in_sizes[1] / 64;
  const int NT = E + N;

  char* ws = (char*)d_ws;
  size_t o = 0;
  auto alloc = [&](size_t bytes) { size_t r = o; o += (bytes + 255) & ~(size_t)255; return r; };
  __bf16* xw1   = (__bf16*)(ws + alloc((size_t)N * 512 * 2));
  __bf16* x1    = (__bf16*)(ws + alloc((size_t)N * 512 * 2));
  __bf16* xw2   = (__bf16*)(ws + alloc((size_t)N * 256 * 2));
  float* out2   = (float*)(ws + alloc((size_t)N * 256 * 4));
  __bf16* embb  = (__bf16*)(ws + alloc((size_t)N * 64 * 2));
  __bf16* W1T   = (__bf16*)(ws + alloc((size_t)512 * 64 * 2));
  __bf16* W2T   = (__bf16*)(ws + alloc((size_t)256 * 512 * 2));
  float* as1    = (float*)(ws + alloc((size_t)N * 4 * 4));
  float* ad1    = (float*)(ws + alloc((size_t)N * 4 * 4));
  float* as2    = (float*)(ws + alloc((size_t)N * 4));
  float* ad2    = (float*)(ws + alloc((size_t)N * 4));
  size_t zbeg = o;
  int* deg      = (int*)(ws + alloc((size_t)N * 4));
  int* cursor   = (int*)(ws + alloc((size_t)N * 4));
  size_t zend = o;
  int* off      = (int*)(ws + alloc((size_t)(N + 1) * 4));
  int* csr_src  = (int*)(ws + alloc((size_t)NT * 4));
  float* Vs1    = (float*)(ws + alloc(64 * 4 * 4));
  float* Vd1    = (float*)(ws + alloc(64 * 4 * 4));
  float* vs2    = (float*)(ws + alloc(512 * 4));
  float* vd2    = (float*)(ws + alloc(512 * 4));

  hipMemsetAsync(ws + zbeg, 0, zend - zbeg, stream);
  hipMemsetAsync(d_out, 0, (size_t)out_size * 4, stream);

  // prep: alpha vectors, bf16 conversions, weight transposes
  prep_v1_kernel<<<1, 256, 0, stream>>>(W1, as1w, ad1w, Vs1, Vd1);
  prep_v2_kernel<<<1, 512, 0, stream>>>(W2, as2w, ad2w, vs2, vd2);
  f32_to_bf16_kernel<<<(N * 64 / 4 + 255) / 256, 256, 0, stream>>>(emb, embb, (size_t)N * 64 / 4);
  transpose_bf16_kernel<<<(64 * 512 + 255) / 256, 256, 0, stream>>>(W1, W1T, 64, 512);
  transpose_bf16_kernel<<<(512 * 256 + 255) / 256, 256, 0, stream>>>(W2, W2T, 512, 256);

  // CSR build (edge_index only)
  int eb = (NT + 255) / 256;
  deg_kernel<<<eb, 256, 0, stream>>>(ei, E, NT, deg);
  exscan_kernel<<<1, 1024, 0, stream>>>(deg, off, N);
  scatter_kernel<<<eb, 256, 0, stream>>>(ei, E, NT, off, cursor, csr_src);

  // layer 1 GEMM: xw1[N,512] = embb[N,64] @ W1T[512,64]^T
  dim3 g1((N + 127) / 128, 512 / 128);
  gemm_bf16_kernel<<<g1, 256, 0, stream>>>(embb, W1T, xw1, N, 512, 64);

  int nb = (N + 255) / 256;
  alpha_nodes_kernel<4><<<nb, 256, 0, stream>>>(emb, Vs1, Vd1, as1, ad1, N, 64);

  // layer 1 fused softmax+aggregation (+bias+ELU), bf16 out
  aggregate_fused_kernel<<<N, 128, 0, stream>>>(off, csr_src, xw1, as1, ad1, b1,
                                                x1, nullptr, 4, 512, 7, 1);

  // layer 2 GEMM: xw2[N,256] = x1[N,512] @ W2T[256,512]^T
  dim3 g2((N + 127) / 128, 256 / 128);
  gemm_bf16_kernel<<<g2, 256, 0, stream>>>(x1, W2T, xw2, N, 256, 512);

  alpha_nodes_bf16_kernel<<<nb, 256, 0, stream>>>(x1, vs2, vd2, as2, ad2, N, 512);

  // layer 2 fused softmax+aggregation (+bias), fp32 out
  aggregate_fused_kernel<<<N, 64, 0, stream>>>(off, csr_src, xw2, as2, ad2, b2,
                                               nullptr, out2, 1, 256, 8, 0);

  mean_reduce_kernel<<<256, 256, 0, stream>>>(out2, out, N);
  if (out_size > 256) {
    bcast_kernel<<<(out_size + 255) / 256, 256, 0, stream>>>(out, out_size);
  }
}

// Round 4
// 482.181 us; speedup vs baseline: 2.7080x; 1.0096x over previous
//
#include <hip/hip_runtime.h>
#include <cstdint>
#include <cstddef>

#define NEG_SLOPE 0.2f

typedef __bf16 bf16x8 __attribute__((ext_vector_type(8)));
typedef __bf16 bf16x4 __attribute__((ext_vector_type(4)));
typedef float f32x4 __attribute__((ext_vector_type(4)));

// ---------- tiny prep: V vectors for alpha computation ----------
__global__ void prep_v1_kernel(const float* __restrict__ W1, const float* __restrict__ as1,
                               const float* __restrict__ ad1, float* __restrict__ Vs,
                               float* __restrict__ Vd) {
  int k = threadIdx.x >> 2, h = threadIdx.x & 3;
  const float* w = W1 + k * 512 + h * 128;
  const float* a1 = as1 + h * 128;
  const float* a2 = ad1 + h * 128;
  float s = 0.f, d = 0.f;
  for (int c = 0; c < 128; ++c) { float wv = w[c]; s += wv * a1[c]; d += wv * a2[c]; }
  Vs[k * 4 + h] = s; Vd[k * 4 + h] = d;
}

__global__ void prep_v2_kernel(const float* __restrict__ W2, const float* __restrict__ as2,
                               const float* __restrict__ ad2, float* __restrict__ vs,
                               float* __restrict__ vd) {
  int k = blockIdx.x * blockDim.x + threadIdx.x;
  if (k >= 512) return;
  const float* w = W2 + k * 256;
  float s = 0.f, d = 0.f;
  for (int c = 0; c < 256; ++c) { float wv = w[c]; s += wv * as2[c]; d += wv * ad2[c]; }
  vs[k] = s; vd[k] = d;
}

// ---------- fused emb -> bf16 + alpha1 ----------
__global__ void emb_prep_kernel(const float* __restrict__ emb, const float* __restrict__ Vs,
                                const float* __restrict__ Vd, __bf16* __restrict__ embb,
                                float* __restrict__ as_, float* __restrict__ ad_, int n) {
  __shared__ float sVs[256];
  __shared__ float sVd[256];
  for (int i = threadIdx.x; i < 256; i += blockDim.x) { sVs[i] = Vs[i]; sVd[i] = Vd[i]; }
  __syncthreads();
  int node = blockIdx.x * blockDim.x + threadIdx.x;
  if (node >= n) return;
  const float* xr = emb + (size_t)node * 64;
  __bf16* br = embb + (size_t)node * 64;
  float accs[4] = {}, accd[4] = {};
  for (int k = 0; k < 64; k += 4) {
    float4 xv = *(const float4*)(xr + k);
    bf16x4 o;
    o[0] = (__bf16)xv.x; o[1] = (__bf16)xv.y; o[2] = (__bf16)xv.z; o[3] = (__bf16)xv.w;
    *(bf16x4*)(br + k) = o;
#pragma unroll
    for (int h = 0; h < 4; ++h) {
      accs[h] += xv.x * sVs[(k + 0) * 4 + h] + xv.y * sVs[(k + 1) * 4 + h] +
                 xv.z * sVs[(k + 2) * 4 + h] + xv.w * sVs[(k + 3) * 4 + h];
      accd[h] += xv.x * sVd[(k + 0) * 4 + h] + xv.y * sVd[(k + 1) * 4 + h] +
                 xv.z * sVd[(k + 2) * 4 + h] + xv.w * sVd[(k + 3) * 4 + h];
    }
  }
#pragma unroll
  for (int h = 0; h < 4; ++h) {
    as_[(size_t)node * 4 + h] = accs[h];
    ad_[(size_t)node * 4 + h] = accd[h];
  }
}

// ---------- weight transpose ----------
__global__ void transpose_bf16_kernel(const float* __restrict__ in, __bf16* __restrict__ out,
                                      int K, int N) {
  int idx = blockIdx.x * blockDim.x + threadIdx.x;
  if (idx >= K * N) return;
  int n = idx / K, k = idx - n * K;
  out[idx] = (__bf16)in[(size_t)k * N + n];
}

// ---------- bf16 MFMA GEMM: C[M,N] = A[M,K] @ BT[N,K]^T ----------
__global__ __launch_bounds__(256) void gemm_bf16_kernel(const __bf16* __restrict__ A,
                                                        const __bf16* __restrict__ BT,
                                                        __bf16* __restrict__ C,
                                                        int M, int N, int K) {
  __shared__ __bf16 Asl[128 * 32];
  __shared__ __bf16 Bsl[128 * 32];
  int tid = threadIdx.x;
  int m0 = blockIdx.x * 128, n0 = blockIdx.y * 128;
  int wave = tid >> 6, lane = tid & 63;
  int wm = (wave >> 1) * 64, wn = (wave & 1) * 64;
  int l15 = lane & 15, kg = lane >> 4;
  f32x4 acc[4][4] = {};
  for (int k0 = 0; k0 < K; k0 += 32) {
#pragma unroll
    for (int i = 0; i < 2; ++i) {
      int c = tid + i * 256;
      int row = c >> 2, off = (c & 3) * 8;
      bf16x8 va = {};
      int gr = m0 + row;
      if (gr < M) va = *(const bf16x8*)(A + (size_t)gr * K + k0 + off);
      *(bf16x8*)(&Asl[row * 32 + off]) = va;
      bf16x8 vb = *(const bf16x8*)(BT + (size_t)(n0 + row) * K + k0 + off);
      *(bf16x8*)(&Bsl[row * 32 + off]) = vb;
    }
    __syncthreads();
    bf16x8 af[4], bfr[4];
#pragma unroll
    for (int f = 0; f < 4; ++f) {
      af[f]  = *(const bf16x8*)(&Asl[(wm + f * 16 + l15) * 32 + kg * 8]);
      bfr[f] = *(const bf16x8*)(&Bsl[(wn + f * 16 + l15) * 32 + kg * 8]);
    }
#pragma unroll
    for (int i = 0; i < 4; ++i)
#pragma unroll
      for (int j = 0; j < 4; ++j)
        acc[i][j] = __builtin_amdgcn_mfma_f32_16x16x32_bf16(af[i], bfr[j], acc[i][j], 0, 0, 0);
    __syncthreads();
  }
#pragma unroll
  for (int i = 0; i < 4; ++i)
#pragma unroll
    for (int j = 0; j < 4; ++j)
#pragma unroll
      for (int r = 0; r < 4; ++r) {
        int row = m0 + wm + i * 16 + kg * 4 + r;
        int col = n0 + wn + j * 16 + l15;
        if (row < M) C[(size_t)row * N + col] = (__bf16)acc[i][j][r];
      }
}

// ---------- CSR build ----------
// degree over REAL edges only (self-loops are an implicit +1 added in the scan)
__global__ void deg_kernel(const int* __restrict__ ei, int E, int* __restrict__ deg) {
  int t = blockIdx.x * blockDim.x + threadIdx.x;
  int base = t * 4;
  if (base >= E) return;
  if (base + 4 <= E) {
    int4 d4 = *(const int4*)(ei + E + base);
    atomicAdd(&deg[d4.x], 1);
    atomicAdd(&deg[d4.y], 1);
    atomicAdd(&deg[d4.z], 1);
    atomicAdd(&deg[d4.w], 1);
  } else {
    for (int e = base; e < E; ++e) atomicAdd(&deg[ei[E + e]], 1);
  }
}

// two-level exclusive scan of (deg[i]+1)
__global__ void scan_reduce_kernel(const int* __restrict__ deg, int* __restrict__ partial, int n) {
  __shared__ int ws[4];
  int i = blockIdx.x * 256 + threadIdx.x;
  int v = (i < n) ? deg[i] + 1 : 0;
  int lane = threadIdx.x & 63, w = threadIdx.x >> 6;
#pragma unroll
  for (int s = 32; s; s >>= 1) v += __shfl_down(v, s, 64);
  if (lane == 0) ws[w] = v;
  __syncthreads();
  if (threadIdx.x == 0) partial[blockIdx.x] = ws[0] + ws[1] + ws[2] + ws[3];
}

__global__ void scan_partials_kernel(int* __restrict__ partial, int nb) {
  __shared__ int buf[256];
  int t = threadIdx.x;
  int v = (t < nb) ? partial[t] : 0;
  buf[t] = v;
  __syncthreads();
  for (int s = 1; s < 256; s <<= 1) {
    int x = (t >= s) ? buf[t - s] : 0;
    __syncthreads();
    buf[t] += x;
    __syncthreads();
  }
  if (t < nb) partial[t] = buf[t] - v;  // exclusive
}

__global__ void scan_final_kernel(const int* __restrict__ deg, const int* __restrict__ partial,
                                  int* __restrict__ off, int n) {
  __shared__ int ws[4];
  int b = blockIdx.x, t = threadIdx.x;
  int i = b * 256 + t;
  int v = (i < n) ? deg[i] + 1 : 0;
  int lane = t & 63, w = t >> 6;
  int x = v;
#pragma unroll
  for (int s = 1; s < 64; s <<= 1) {
    int tt = __shfl_up(x, s, 64);
    if (lane >= s) x += tt;
  }
  if (lane == 63) ws[w] = x;
  __syncthreads();
  int wo = 0;
  for (int k = 0; k < w; ++k) wo += ws[k];
  int base = partial[b];
  if (i < n) off[i] = base + wo + x - v;
  if (i == n - 1) off[n] = base + wo + x;
}

// scatter REAL edges (slots [off[d], off[d]+real_cnt)); self-loop gets off[d+1]-1
__global__ void scatter_kernel(const int* __restrict__ ei, int E, const int* __restrict__ off,
                               int* __restrict__ cursor, int* __restrict__ csr_src) {
  int e = blockIdx.x * blockDim.x + threadIdx.x;
  if (e >= E) return;
  int s = ei[e], d = ei[E + e];
  int p = atomicAdd(&cursor[d], 1);
  csr_src[off[d] + p] = s;
}

__global__ void selfloop_kernel(const int* __restrict__ off, int* __restrict__ csr_src, int n) {
  int d = blockIdx.x * blockDim.x + threadIdx.x;
  if (d < n) csr_src[off[d + 1] - 1] = d;
}

// ---------- layer-1 fused softmax+aggregate (+bias+ELU) + alpha2 epilogue ----------
// 128 threads = 2 waves, wave w handles dst node blockIdx*2+w; 64 lanes x bf16x8 = 1024B row
__global__ __launch_bounds__(128) void aggregate1_kernel(
    const int* __restrict__ off, const int* __restrict__ csr_src, const __bf16* __restrict__ xw,
    const float* __restrict__ as_, const float* __restrict__ ad_, const float* __restrict__ bias,
    const float* __restrict__ vs2, const float* __restrict__ vd2,
    __bf16* __restrict__ x1, float* __restrict__ as2, float* __restrict__ ad2) {
  int d = blockIdx.x * 2 + (threadIdx.x >> 6);
  int lane = threadIdx.x & 63;
  int c0 = lane * 8;
  int h = lane >> 4;
  float adv = ad_[(size_t)d * 4 + h];
  float acc[8] = {};
  float wsum = 0.f;
  int beg = off[d], end = off[d + 1];
#pragma unroll 4
  for (int i = beg; i < end; ++i) {
    int s = __builtin_amdgcn_readfirstlane(csr_src[i]);
    float asv = as_[(size_t)s * 4 + h];
    float l = asv + adv;
    l = l >= 0.f ? l : NEG_SLOPE * l;
    float w = __expf(l);
    wsum += w;
    bf16x8 v = *(const bf16x8*)(xw + (size_t)s * 512 + c0);
#pragma unroll
    for (int j = 0; j < 8; ++j) acc[j] += (float)v[j] * w;
  }
  float inv = 1.0f / wsum;
  float4 bv0 = *(const float4*)(bias + c0);
  float4 bv1 = *(const float4*)(bias + c0 + 4);
  float b[8] = {bv0.x, bv0.y, bv0.z, bv0.w, bv1.x, bv1.y, bv1.z, bv1.w};
  float4 v20 = *(const float4*)(vs2 + c0);
  float4 v21 = *(const float4*)(vs2 + c0 + 4);
  float4 v30 = *(const float4*)(vd2 + c0);
  float4 v31 = *(const float4*)(vd2 + c0 + 4);
  float vs[8] = {v20.x, v20.y, v20.z, v20.w, v21.x, v21.y, v21.z, v21.w};
  float vd[8] = {v30.x, v30.y, v30.z, v30.w, v31.x, v31.y, v31.z, v31.w};
  float ps = 0.f, pd = 0.f;
  bf16x8 r;
#pragma unroll
  for (int j = 0; j < 8; ++j) {
    float a = acc[j] * inv + b[j];
    a = a > 0.f ? a : __expf(a) - 1.f;   // ELU
    r[j] = (__bf16)a;
    ps += a * vs[j];
    pd += a * vd[j];
  }
  *(bf16x8*)(x1 + (size_t)d * 512 + c0) = r;
#pragma unroll
  for (int s = 32; s; s >>= 1) {
    ps += __shfl_down(ps, s, 64);
    pd += __shfl_down(pd, s, 64);
  }
  if (lane == 0) { as2[d] = ps; ad2[d] = pd; }
}

// ---------- layer-2 fused softmax+aggregate (+bias), fp32 out ----------
__global__ __launch_bounds__(128) void aggregate2_kernel(
    const int* __restrict__ off, const int* __restrict__ csr_src, const __bf16* __restrict__ xw,
    const float* __restrict__ as_, const float* __restrict__ ad_, const float* __restrict__ bias,
    float* __restrict__ out2) {
  int d = blockIdx.x * 2 + (threadIdx.x >> 6);
  int lane = threadIdx.x & 63;
  int c0 = lane * 4;
  float adv = ad_[d];
  float a0 = 0.f, a1 = 0.f, a2 = 0.f, a3 = 0.f, wsum = 0.f;
  int beg = off[d], end = off[d + 1];
#pragma unroll 4
  for (int i = beg; i < end; ++i) {
    int s = __builtin_amdgcn_readfirstlane(csr_src[i]);
    float l = as_[s] + adv;
    l = l >= 0.f ? l : NEG_SLOPE * l;
    float w = __expf(l);
    wsum += w;
    bf16x4 v = *(const bf16x4*)(xw + (size_t)s * 256 + c0);
    a0 += (float)v[0] * w; a1 += (float)v[1] * w; a2 += (float)v[2] * w; a3 += (float)v[3] * w;
  }
  float inv = 1.0f / wsum;
  float4 bv = *(const float4*)(bias + c0);
  float4 r = make_float4(a0 * inv + bv.x, a1 * inv + bv.y, a2 * inv + bv.z, a3 * inv + bv.w);
  *(float4*)(out2 + (size_t)d * 256 + c0) = r;
}

// ---------- final mean over nodes ----------
__global__ void mean_reduce_kernel(const float* __restrict__ out2, float* __restrict__ dout, int n) {
  int col = threadIdx.x;  // 256
  float acc = 0.f;
  for (int r = blockIdx.x; r < n; r += gridDim.x) acc += out2[(size_t)r * 256 + col];
  atomicAdd(&dout[col], acc * (1.0f / (float)n));
}

__global__ void bcast_kernel(float* __restrict__ dout, int total) {
  int i = blockIdx.x * blockDim.x + threadIdx.x;
  if (i >= 256 && i < total) dout[i] = dout[i & 255];
}

// ---------- host ----------
extern "C" void kernel_launch(void* const* d_in, const int* in_sizes, int n_in,
                              void* d_out, int out_size, void* d_ws, size_t ws_size,
                              hipStream_t stream) {
  const int* ei = (const int*)d_in[0];
  const float* emb = (const float*)d_in[1];
  const float* W1 = (const float*)d_in[2];
  const float* as1w = (const float*)d_in[3];
  const float* ad1w = (const float*)d_in[4];
  const float* b1 = (const float*)d_in[5];
  const float* W2 = (const float*)d_in[6];
  const float* as2w = (const float*)d_in[7];
  const float* ad2w = (const float*)d_in[8];
  const float* b2 = (const float*)d_in[9];
  float* out = (float*)d_out;

  const int E = in_sizes[0] / 2;
  const int N = in_sizes[1] / 64;
  const int NT = E + N;

  char* ws = (char*)d_ws;
  size_t o = 0;
  auto alloc = [&](size_t bytes) { size_t r = o; o += (bytes + 255) & ~(size_t)255; return r; };
  __bf16* xw1   = (__bf16*)(ws + alloc((size_t)N * 512 * 2));
  __bf16* x1    = (__bf16*)(ws + alloc((size_t)N * 512 * 2));
  __bf16* xw2   = (__bf16*)(ws + alloc((size_t)N * 256 * 2));
  float* out2   = (float*)(ws + alloc((size_t)N * 256 * 4));
  __bf16* embb  = (__bf16*)(ws + alloc((size_t)N * 64 * 2));
  __bf16* W1T   = (__bf16*)(ws + alloc((size_t)512 * 64 * 2));
  __bf16* W2T   = (__bf16*)(ws + alloc((size_t)256 * 512 * 2));
  float* as1    = (float*)(ws + alloc((size_t)N * 4 * 4));
  float* ad1    = (float*)(ws + alloc((size_t)N * 4 * 4));
  float* as2    = (float*)(ws + alloc((size_t)N * 4));
  float* ad2    = (float*)(ws + alloc((size_t)N * 4));
  size_t zbeg = o;
  int* deg      = (int*)(ws + alloc((size_t)N * 4));
  int* cursor   = (int*)(ws + alloc((size_t)N * 4));
  size_t zend = o;
  int* off      = (int*)(ws + alloc((size_t)(N + 1) * 4));
  int* partial  = (int*)(ws + alloc(256 * 4));
  int* csr_src  = (int*)(ws + alloc((size_t)NT * 4));
  float* Vs1    = (float*)(ws + alloc(64 * 4 * 4));
  float* Vd1    = (float*)(ws + alloc(64 * 4 * 4));
  float* vs2    = (float*)(ws + alloc(512 * 4));
  float* vd2    = (float*)(ws + alloc(512 * 4));

  hipMemsetAsync(ws + zbeg, 0, zend - zbeg, stream);
  hipMemsetAsync(d_out, 0, (size_t)out_size * 4, stream);

  // prep
  prep_v1_kernel<<<1, 256, 0, stream>>>(W1, as1w, ad1w, Vs1, Vd1);
  prep_v2_kernel<<<1, 512, 0, stream>>>(W2, as2w, ad2w, vs2, vd2);
  transpose_bf16_kernel<<<(64 * 512 + 255) / 256, 256, 0, stream>>>(W1, W1T, 64, 512);
  transpose_bf16_kernel<<<(512 * 256 + 255) / 256, 256, 0, stream>>>(W2, W2T, 512, 256);
  int nb = (N + 255) / 256;
  emb_prep_kernel<<<nb, 256, 0, stream>>>(emb, Vs1, Vd1, embb, as1, ad1, N);

  // CSR build
  deg_kernel<<<(E / 4 + 255) / 256, 256, 0, stream>>>(ei, E, deg);
  scan_reduce_kernel<<<nb, 256, 0, stream>>>(deg, partial, N);
  scan_partials_kernel<<<1, 256, 0, stream>>>(partial, nb);
  scan_final_kernel<<<nb, 256, 0, stream>>>(deg, partial, off, N);
  scatter_kernel<<<(E + 255) / 256, 256, 0, stream>>>(ei, E, off, cursor, csr_src);
  selfloop_kernel<<<nb, 256, 0, stream>>>(off, csr_src, N);

  // layer 1
  dim3 g1((N + 127) / 128, 512 / 128);
  gemm_bf16_kernel<<<g1, 256, 0, stream>>>(embb, W1T, xw1, N, 512, 64);
  aggregate1_kernel<<<N / 2, 128, 0, stream>>>(off, csr_src, xw1, as1, ad1, b1,
                                               vs2, vd2, x1, as2, ad2);

  // layer 2
  dim3 g2((N + 127) / 128, 256 / 128);
  gemm_bf16_kernel<<<g2, 256, 0, stream>>>(x1, W2T, xw2, N, 256, 512);
  aggregate2_kernel<<<N / 2, 128, 0, stream>>>(off, csr_src, xw2, as2, ad2, b2, out2);

  mean_reduce_kernel<<<256, 256, 0, stream>>>(out2, out, N);
  if (out_size > 256) {
    bcast_kernel<<<(out_size + 255) / 256, 256, 0, stream>>>(out, out_size);
  }
}

// Round 5
// 398.146 us; speedup vs baseline: 3.2796x; 1.2111x over previous
//
#include <hip/hip_runtime.h>
#include <cstdint>
#include <cstddef>

#define NEG_SLOPE 0.2f

typedef __bf16 bf16x8 __attribute__((ext_vector_type(8)));
typedef __bf16 bf16x4 __attribute__((ext_vector_type(4)));
typedef float f32x4 __attribute__((ext_vector_type(4)));

// ---------- tiny prep: V vectors for alpha computation ----------
__global__ void prep_v1_kernel(const float* __restrict__ W1, const float* __restrict__ as1,
                               const float* __restrict__ ad1, float* __restrict__ Vs,
                               float* __restrict__ Vd) {
  int k = threadIdx.x >> 2, h = threadIdx.x & 3;
  const float* w = W1 + k * 512 + h * 128;
  const float* a1 = as1 + h * 128;
  const float* a2 = ad1 + h * 128;
  float s = 0.f, d = 0.f;
  for (int c = 0; c < 128; ++c) { float wv = w[c]; s += wv * a1[c]; d += wv * a2[c]; }
  Vs[k * 4 + h] = s; Vd[k * 4 + h] = d;
}

__global__ void prep_v2_kernel(const float* __restrict__ W2, const float* __restrict__ as2,
                               const float* __restrict__ ad2, float* __restrict__ vs,
                               float* __restrict__ vd) {
  int k = blockIdx.x * blockDim.x + threadIdx.x;
  if (k >= 512) return;
  const float* w = W2 + k * 256;
  float s = 0.f, d = 0.f;
  for (int c = 0; c < 256; ++c) { float wv = w[c]; s += wv * as2[c]; d += wv * ad2[c]; }
  vs[k] = s; vd[k] = d;
}

// ---------- fused emb -> bf16 + alpha1 ----------
__global__ void emb_prep_kernel(const float* __restrict__ emb, const float* __restrict__ Vs,
                                const float* __restrict__ Vd, __bf16* __restrict__ embb,
                                float* __restrict__ as_, float* __restrict__ ad_, int n) {
  __shared__ float sVs[256];
  __shared__ float sVd[256];
  for (int i = threadIdx.x; i < 256; i += blockDim.x) { sVs[i] = Vs[i]; sVd[i] = Vd[i]; }
  __syncthreads();
  int node = blockIdx.x * blockDim.x + threadIdx.x;
  if (node >= n) return;
  const float* xr = emb + (size_t)node * 64;
  __bf16* br = embb + (size_t)node * 64;
  float accs[4] = {}, accd[4] = {};
  for (int k = 0; k < 64; k += 4) {
    float4 xv = *(const float4*)(xr + k);
    bf16x4 o;
    o[0] = (__bf16)xv.x; o[1] = (__bf16)xv.y; o[2] = (__bf16)xv.z; o[3] = (__bf16)xv.w;
    *(bf16x4*)(br + k) = o;
#pragma unroll
    for (int h = 0; h < 4; ++h) {
      accs[h] += xv.x * sVs[(k + 0) * 4 + h] + xv.y * sVs[(k + 1) * 4 + h] +
                 xv.z * sVs[(k + 2) * 4 + h] + xv.w * sVs[(k + 3) * 4 + h];
      accd[h] += xv.x * sVd[(k + 0) * 4 + h] + xv.y * sVd[(k + 1) * 4 + h] +
                 xv.z * sVd[(k + 2) * 4 + h] + xv.w * sVd[(k + 3) * 4 + h];
    }
  }
#pragma unroll
  for (int h = 0; h < 4; ++h) {
    as_[(size_t)node * 4 + h] = accs[h];
    ad_[(size_t)node * 4 + h] = accd[h];
  }
}

// ---------- weight transpose: W1 [64,512] fp32 -> W1T [512,64] bf16 ----------
__global__ void transpose_bf16_kernel(const float* __restrict__ in, __bf16* __restrict__ out,
                                      int K, int N) {
  int idx = blockIdx.x * blockDim.x + threadIdx.x;
  if (idx >= K * N) return;
  int n = idx / K, k = idx - n * K;
  out[idx] = (__bf16)in[(size_t)k * N + n];
}

// ---------- CSR build ----------
__global__ void deg_kernel(const int* __restrict__ ei, int E, int* __restrict__ deg) {
  int t = blockIdx.x * blockDim.x + threadIdx.x;
  int base = t * 4;
  if (base >= E) return;
  if (base + 4 <= E) {
    int4 d4 = *(const int4*)(ei + E + base);
    atomicAdd(&deg[d4.x], 1);
    atomicAdd(&deg[d4.y], 1);
    atomicAdd(&deg[d4.z], 1);
    atomicAdd(&deg[d4.w], 1);
  } else {
    for (int e = base; e < E; ++e) atomicAdd(&deg[ei[E + e]], 1);
  }
}

__global__ void scan_reduce_kernel(const int* __restrict__ deg, int* __restrict__ partial, int n) {
  __shared__ int ws[4];
  int i = blockIdx.x * 256 + threadIdx.x;
  int v = (i < n) ? deg[i] + 1 : 0;
  int lane = threadIdx.x & 63, w = threadIdx.x >> 6;
#pragma unroll
  for (int s = 32; s; s >>= 1) v += __shfl_down(v, s, 64);
  if (lane == 0) ws[w] = v;
  __syncthreads();
  if (threadIdx.x == 0) partial[blockIdx.x] = ws[0] + ws[1] + ws[2] + ws[3];
}

__global__ void scan_partials_kernel(int* __restrict__ partial, int nb) {
  __shared__ int buf[256];
  int t = threadIdx.x;
  int v = (t < nb) ? partial[t] : 0;
  buf[t] = v;
  __syncthreads();
  for (int s = 1; s < 256; s <<= 1) {
    int x = (t >= s) ? buf[t - s] : 0;
    __syncthreads();
    buf[t] += x;
    __syncthreads();
  }
  if (t < nb) partial[t] = buf[t] - v;  // exclusive
}

__global__ void scan_final_kernel(const int* __restrict__ deg, const int* __restrict__ partial,
                                  int* __restrict__ off, int n) {
  __shared__ int ws[4];
  int b = blockIdx.x, t = threadIdx.x;
  int i = b * 256 + t;
  int v = (i < n) ? deg[i] + 1 : 0;
  int lane = t & 63, w = t >> 6;
  int x = v;
#pragma unroll
  for (int s = 1; s < 64; s <<= 1) {
    int tt = __shfl_up(x, s, 64);
    if (lane >= s) x += tt;
  }
  if (lane == 63) ws[w] = x;
  __syncthreads();
  int wo = 0;
  for (int k = 0; k < w; ++k) wo += ws[k];
  int base = partial[b];
  if (i < n) off[i] = base + wo + x - v;
  if (i == n - 1) off[n] = base + wo + x;
}

__global__ void scatter_kernel(const int* __restrict__ ei, int E, const int* __restrict__ off,
                               int* __restrict__ cursor, int* __restrict__ csr_src) {
  int e = blockIdx.x * blockDim.x + threadIdx.x;
  if (e >= E) return;
  int s = ei[e], d = ei[E + e];
  int p = atomicAdd(&cursor[d], 1);
  csr_src[off[d] + p] = s;
}

__global__ void selfloop_kernel(const int* __restrict__ off, int* __restrict__ csr_src, int n) {
  int d = blockIdx.x * blockDim.x + threadIdx.x;
  if (d < n) csr_src[off[d + 1] - 1] = d;
}

// ---------- layer-1 aggregation in EMBEDDING space ----------
// aggE[d, h, 0:64] = (sum_e w_e^h * embb[s_e, :]) / (sum_e w_e^h), bf16
// one wave per dst, lane = channel; per-edge 128B gather from 6.4MB L2-resident table
__global__ __launch_bounds__(128) void agg_emb_kernel(
    const int* __restrict__ off, const int* __restrict__ csr_src,
    const __bf16* __restrict__ embb, const float* __restrict__ as_,
    const float* __restrict__ ad_, __bf16* __restrict__ aggE) {
  int d = blockIdx.x * 2 + (threadIdx.x >> 6);
  int lane = threadIdx.x & 63;
  float4 adv = *(const float4*)(ad_ + (size_t)d * 4);
  float acc0 = 0.f, acc1 = 0.f, acc2 = 0.f, acc3 = 0.f;
  float ws0 = 0.f, ws1 = 0.f, ws2 = 0.f, ws3 = 0.f;
  int beg = off[d], end = off[d + 1];
#pragma unroll 2
  for (int i = beg; i < end; ++i) {
    int s = __builtin_amdgcn_readfirstlane(csr_src[i]);
    float4 asv = *(const float4*)(as_ + (size_t)s * 4);
    float l0 = asv.x + adv.x; l0 = l0 >= 0.f ? l0 : NEG_SLOPE * l0;
    float l1 = asv.y + adv.y; l1 = l1 >= 0.f ? l1 : NEG_SLOPE * l1;
    float l2 = asv.z + adv.z; l2 = l2 >= 0.f ? l2 : NEG_SLOPE * l2;
    float l3 = asv.w + adv.w; l3 = l3 >= 0.f ? l3 : NEG_SLOPE * l3;
    float w0 = __expf(l0), w1 = __expf(l1), w2 = __expf(l2), w3 = __expf(l3);
    float v = (float)embb[(size_t)s * 64 + lane];
    acc0 += w0 * v; acc1 += w1 * v; acc2 += w2 * v; acc3 += w3 * v;
    ws0 += w0; ws1 += w1; ws2 += w2; ws3 += w3;
  }
  __bf16* o = aggE + (size_t)d * 256 + lane;
  o[0]   = (__bf16)(acc0 / ws0);
  o[64]  = (__bf16)(acc1 / ws1);
  o[128] = (__bf16)(acc2 / ws2);
  o[192] = (__bf16)(acc3 / ws3);
}

// ---------- reconstruct x1: per-head GEMM [N,64]@[64,128] + bias + ELU ----------
// grid.z = head; A = aggE[:, h*64 + k] (lda 256); B = W1T rows h*128.. (ldb 64);
// C = x1[:, h*128 + c] (ldc 512), bf16 out
__global__ __launch_bounds__(256) void gemm1p_kernel(const __bf16* __restrict__ aggE,
                                                     const __bf16* __restrict__ W1T,
                                                     const float* __restrict__ b1,
                                                     __bf16* __restrict__ x1, int M) {
  __shared__ __bf16 Asl[128 * 72];
  __shared__ __bf16 Bsl[128 * 72];
  int tid = threadIdx.x;
  int h = blockIdx.z;
  int m0 = blockIdx.x * 128;
  int wave = tid >> 6, lane = tid & 63;
  int wm = (wave >> 1) * 64, wn = (wave & 1) * 64;
  int l15 = lane & 15, kg = lane >> 4;
#pragma unroll
  for (int i = 0; i < 4; ++i) {
    int c = tid + i * 256;                 // 0..1023
    int row = c >> 3, off = (c & 7) * 8;   // row 0..127, off 0..56
    bf16x8 va = {};
    int gr = m0 + row;
    if (gr < M) va = *(const bf16x8*)(aggE + (size_t)gr * 256 + h * 64 + off);
    *(bf16x8*)(&Asl[row * 72 + off]) = va;
    bf16x8 vb = *(const bf16x8*)(W1T + ((size_t)h * 128 + row) * 64 + off);
    *(bf16x8*)(&Bsl[row * 72 + off]) = vb;
  }
  __syncthreads();
  f32x4 acc[4][4] = {};
#pragma unroll
  for (int ks = 0; ks < 2; ++ks) {
    bf16x8 af[4], bfr[4];
#pragma unroll
    for (int f = 0; f < 4; ++f) {
      af[f]  = *(const bf16x8*)(&Asl[(wm + f * 16 + l15) * 72 + kg * 8 + ks * 32]);
      bfr[f] = *(const bf16x8*)(&Bsl[(wn + f * 16 + l15) * 72 + kg * 8 + ks * 32]);
    }
#pragma unroll
    for (int i = 0; i < 4; ++i)
#pragma unroll
      for (int j = 0; j < 4; ++j)
        acc[i][j] = __builtin_amdgcn_mfma_f32_16x16x32_bf16(af[i], bfr[j], acc[i][j], 0, 0, 0);
  }
#pragma unroll
  for (int i = 0; i < 4; ++i)
#pragma unroll
    for (int j = 0; j < 4; ++j)
#pragma unroll
      for (int r = 0; r < 4; ++r) {
        int row = m0 + wm + i * 16 + kg * 4 + r;
        int col = wn + j * 16 + l15;       // 0..127 within head
        if (row < M) {
          float a = acc[i][j][r] + b1[h * 128 + col];
          a = a > 0.f ? a : __expf(a) - 1.f;   // ELU
          x1[(size_t)row * 512 + h * 128 + col] = (__bf16)a;
        }
      }
}

// ---------- per-node alpha for layer 2 (bf16 X, H=1) ----------
__global__ void alpha_nodes_bf16_kernel(const __bf16* __restrict__ X, const float* __restrict__ vs,
                                        const float* __restrict__ vd, float* __restrict__ as_,
                                        float* __restrict__ ad_, int n, int K) {
  __shared__ float sVs[512];
  __shared__ float sVd[512];
  for (int i = threadIdx.x; i < K; i += blockDim.x) { sVs[i] = vs[i]; sVd[i] = vd[i]; }
  __syncthreads();
  int node = blockIdx.x * blockDim.x + threadIdx.x;
  if (node >= n) return;
  const __bf16* xr = X + (size_t)node * K;
  float s = 0.f, d = 0.f;
  for (int k = 0; k < K; k += 8) {
    bf16x8 v = *(const bf16x8*)(xr + k);
#pragma unroll
    for (int j = 0; j < 8; ++j) {
      float f = (float)v[j];
      s += f * sVs[k + j];
      d += f * sVd[k + j];
    }
  }
  as_[node] = s; ad_[node] = d;
}

// ---------- layer-2 softmax denom + gamma scatter ----------
// gamma[s] += exp(leaky(as2[s]+ad2[d])) / (Wd * N) over all edges into d
__global__ void wd_gamma_kernel(const int* __restrict__ off, const int* __restrict__ csr_src,
                                const float* __restrict__ as2, const float* __restrict__ ad2,
                                float* __restrict__ gamma, float invN, int n) {
  int d = blockIdx.x * blockDim.x + threadIdx.x;
  if (d >= n) return;
  float adv = ad2[d];
  int beg = off[d], end = off[d + 1];
  float wsum = 0.f;
  for (int i = beg; i < end; ++i) {
    float l = as2[csr_src[i]] + adv;
    l = l >= 0.f ? l : NEG_SLOPE * l;
    wsum += __expf(l);
  }
  float scale = invN / wsum;
  for (int i = beg; i < end; ++i) {
    int s = csr_src[i];
    float l = as2[s] + adv;
    l = l >= 0.f ? l : NEG_SLOPE * l;
    atomicAdd(&gamma[s], __expf(l) * scale);
  }
}

// ---------- weighted column sum: colsum[c] = sum_r gamma[r] * x1[r,c] ----------
__global__ __launch_bounds__(256) void colsum_kernel(const __bf16* __restrict__ x1,
                                                     const float* __restrict__ gamma,
                                                     float* __restrict__ colsum, int n) {
  int c = threadIdx.x;  // 256
  float a0 = 0.f, a1 = 0.f;
  for (int r = blockIdx.x; r < n; r += gridDim.x) {
    float g = gamma[r];
    a0 += g * (float)x1[(size_t)r * 512 + c];
    a1 += g * (float)x1[(size_t)r * 512 + 256 + c];
  }
  atomicAdd(&colsum[c], a0);
  atomicAdd(&colsum[c + 256], a1);
}

// ---------- final matvec: out[c] = colsum . W2[:,c] + b2[c] ----------
__global__ void final_kernel(const float* __restrict__ colsum, const float* __restrict__ W2,
                             const float* __restrict__ b2, float* __restrict__ out) {
  int c = threadIdx.x;  // 256
  int k0 = blockIdx.x * 64;  // 8 blocks x 64 k
  float acc = 0.f;
  for (int k = k0; k < k0 + 64; ++k) acc += colsum[k] * W2[(size_t)k * 256 + c];
  if (blockIdx.x == 0) acc += b2[c];
  atomicAdd(&out[c], acc);
}

__global__ void bcast_kernel(float* __restrict__ dout, int total) {
  int i = blockIdx.x * blockDim.x + threadIdx.x;
  if (i >= 256 && i < total) dout[i] = dout[i & 255];
}

// ---------- host ----------
extern "C" void kernel_launch(void* const* d_in, const int* in_sizes, int n_in,
                              void* d_out, int out_size, void* d_ws, size_t ws_size,
                              hipStream_t stream) {
  const int* ei = (const int*)d_in[0];
  const float* emb = (const float*)d_in[1];
  const float* W1 = (const float*)d_in[2];
  const float* as1w = (const float*)d_in[3];
  const float* ad1w = (const float*)d_in[4];
  const float* b1 = (const float*)d_in[5];
  const float* W2 = (const float*)d_in[6];
  const float* as2w = (const float*)d_in[7];
  const float* ad2w = (const float*)d_in[8];
  const float* b2 = (const float*)d_in[9];
  float* out = (float*)d_out;

  const int E = in_sizes[0] / 2;
  const int N = in_sizes[1] / 64;
  const int NT = E + N;

  char* ws = (char*)d_ws;
  size_t o = 0;
  auto alloc = [&](size_t bytes) { size_t r = o; o += (bytes + 255) & ~(size_t)255; return r; };
  __bf16* embb  = (__bf16*)(ws + alloc((size_t)N * 64 * 2));
  __bf16* aggE  = (__bf16*)(ws + alloc((size_t)N * 256 * 2));
  __bf16* x1    = (__bf16*)(ws + alloc((size_t)N * 512 * 2));
  __bf16* W1T   = (__bf16*)(ws + alloc((size_t)512 * 64 * 2));
  float* as1    = (float*)(ws + alloc((size_t)N * 4 * 4));
  float* ad1    = (float*)(ws + alloc((size_t)N * 4 * 4));
  float* as2    = (float*)(ws + alloc((size_t)N * 4));
  float* ad2    = (float*)(ws + alloc((size_t)N * 4));
  size_t zbeg = o;
  int* deg      = (int*)(ws + alloc((size_t)N * 4));
  int* cursor   = (int*)(ws + alloc((size_t)N * 4));
  float* gamma  = (float*)(ws + alloc((size_t)N * 4));
  float* colsum = (float*)(ws + alloc(512 * 4));
  size_t zend = o;
  int* off      = (int*)(ws + alloc((size_t)(N + 1) * 4));
  int* partial  = (int*)(ws + alloc(256 * 4));
  int* csr_src  = (int*)(ws + alloc((size_t)NT * 4));
  float* Vs1    = (float*)(ws + alloc(64 * 4 * 4));
  float* Vd1    = (float*)(ws + alloc(64 * 4 * 4));
  float* vs2    = (float*)(ws + alloc(512 * 4));
  float* vd2    = (float*)(ws + alloc(512 * 4));

  hipMemsetAsync(ws + zbeg, 0, zend - zbeg, stream);
  hipMemsetAsync(d_out, 0, (size_t)out_size * 4, stream);

  // prep
  prep_v1_kernel<<<1, 256, 0, stream>>>(W1, as1w, ad1w, Vs1, Vd1);
  prep_v2_kernel<<<1, 512, 0, stream>>>(W2, as2w, ad2w, vs2, vd2);
  transpose_bf16_kernel<<<(64 * 512 + 255) / 256, 256, 0, stream>>>(W1, W1T, 64, 512);
  int nb = (N + 255) / 256;
  emb_prep_kernel<<<nb, 256, 0, stream>>>(emb, Vs1, Vd1, embb, as1, ad1, N);

  // CSR build
  deg_kernel<<<(E / 4 + 255) / 256, 256, 0, stream>>>(ei, E, deg);
  scan_reduce_kernel<<<nb, 256, 0, stream>>>(deg, partial, N);
  scan_partials_kernel<<<1, 256, 0, stream>>>(partial, nb);
  scan_final_kernel<<<nb, 256, 0, stream>>>(deg, partial, off, N);
  scatter_kernel<<<(E + 255) / 256, 256, 0, stream>>>(ei, E, off, cursor, csr_src);
  selfloop_kernel<<<nb, 256, 0, stream>>>(off, csr_src, N);

  // layer 1: aggregate in emb space, then reconstruct with per-head GEMM
  agg_emb_kernel<<<N / 2, 128, 0, stream>>>(off, csr_src, embb, as1, ad1, aggE);
  dim3 g1((N + 127) / 128, 1, 4);
  gemm1p_kernel<<<g1, 256, 0, stream>>>(aggE, W1T, b1, x1, N);

  // layer 2 collapsed: alpha2 -> per-dst denom + gamma scatter -> weighted colsum -> matvec
  alpha_nodes_bf16_kernel<<<nb, 256, 0, stream>>>(x1, vs2, vd2, as2, ad2, N, 512);
  wd_gamma_kernel<<<nb, 256, 0, stream>>>(off, csr_src, as2, ad2, gamma, 1.0f / (float)N, N);
  colsum_kernel<<<256, 256, 0, stream>>>(x1, gamma, colsum, N);
  final_kernel<<<8, 256, 0, stream>>>(colsum, W2, b2, out);

  if (out_size > 256) {
    bcast_kernel<<<(out_size + 255) / 256, 256, 0, stream>>>(out, out_size);
  }
}

// Round 6
// 321.835 us; speedup vs baseline: 4.0572x; 1.2371x over previous
//
#include <hip/hip_runtime.h>
#include <cstdint>
#include <cstddef>

#define NEG_SLOPE 0.2f

typedef __bf16 bf16x8 __attribute__((ext_vector_type(8)));
typedef __bf16 bf16x4 __attribute__((ext_vector_type(4)));
typedef float f32x4 __attribute__((ext_vector_type(4)));

// ---------- tiny prep: V vectors for alpha computation ----------
__global__ void prep_v1_kernel(const float* __restrict__ W1, const float* __restrict__ as1,
                               const float* __restrict__ ad1, float* __restrict__ Vs,
                               float* __restrict__ Vd) {
  int k = threadIdx.x >> 2, h = threadIdx.x & 3;
  const float* w = W1 + k * 512 + h * 128;
  const float* a1 = as1 + h * 128;
  const float* a2 = ad1 + h * 128;
  float s = 0.f, d = 0.f;
  for (int c = 0; c < 128; ++c) { float wv = w[c]; s += wv * a1[c]; d += wv * a2[c]; }
  Vs[k * 4 + h] = s; Vd[k * 4 + h] = d;
}

__global__ void prep_v2_kernel(const float* __restrict__ W2, const float* __restrict__ as2,
                               const float* __restrict__ ad2, float* __restrict__ vs,
                               float* __restrict__ vd) {
  int k = blockIdx.x * blockDim.x + threadIdx.x;
  if (k >= 512) return;
  const float* w = W2 + k * 256;
  float s = 0.f, d = 0.f;
  for (int c = 0; c < 256; ++c) { float wv = w[c]; s += wv * as2[c]; d += wv * ad2[c]; }
  vs[k] = s; vd[k] = d;
}

// ---------- fused emb -> bf16 + alpha1 ----------
__global__ void emb_prep_kernel(const float* __restrict__ emb, const float* __restrict__ Vs,
                                const float* __restrict__ Vd, __bf16* __restrict__ embb,
                                float* __restrict__ as_, float* __restrict__ ad_, int n) {
  __shared__ float sVs[256];
  __shared__ float sVd[256];
  for (int i = threadIdx.x; i < 256; i += blockDim.x) { sVs[i] = Vs[i]; sVd[i] = Vd[i]; }
  __syncthreads();
  int node = blockIdx.x * blockDim.x + threadIdx.x;
  if (node >= n) return;
  const float* xr = emb + (size_t)node * 64;
  __bf16* br = embb + (size_t)node * 64;
  float accs[4] = {}, accd[4] = {};
  for (int k = 0; k < 64; k += 4) {
    float4 xv = *(const float4*)(xr + k);
    bf16x4 o;
    o[0] = (__bf16)xv.x; o[1] = (__bf16)xv.y; o[2] = (__bf16)xv.z; o[3] = (__bf16)xv.w;
    *(bf16x4*)(br + k) = o;
#pragma unroll
    for (int h = 0; h < 4; ++h) {
      accs[h] += xv.x * sVs[(k + 0) * 4 + h] + xv.y * sVs[(k + 1) * 4 + h] +
                 xv.z * sVs[(k + 2) * 4 + h] + xv.w * sVs[(k + 3) * 4 + h];
      accd[h] += xv.x * sVd[(k + 0) * 4 + h] + xv.y * sVd[(k + 1) * 4 + h] +
                 xv.z * sVd[(k + 2) * 4 + h] + xv.w * sVd[(k + 3) * 4 + h];
    }
  }
#pragma unroll
  for (int h = 0; h < 4; ++h) {
    as_[(size_t)node * 4 + h] = accs[h];
    ad_[(size_t)node * 4 + h] = accd[h];
  }
}

// ---------- weight transpose: W1 [64,512] fp32 -> W1T [512,64] bf16 ----------
__global__ void transpose_bf16_kernel(const float* __restrict__ in, __bf16* __restrict__ out,
                                      int K, int N) {
  int idx = blockIdx.x * blockDim.x + threadIdx.x;
  if (idx >= K * N) return;
  int n = idx / K, k = idx - n * K;
  out[idx] = (__bf16)in[(size_t)k * N + n];
}

// ---------- CSR build ----------
__global__ void deg_kernel(const int* __restrict__ ei, int E, int* __restrict__ deg) {
  int t = blockIdx.x * blockDim.x + threadIdx.x;
  int base = t * 4;
  if (base >= E) return;
  if (base + 4 <= E) {
    int4 d4 = *(const int4*)(ei + E + base);
    atomicAdd(&deg[d4.x], 1);
    atomicAdd(&deg[d4.y], 1);
    atomicAdd(&deg[d4.z], 1);
    atomicAdd(&deg[d4.w], 1);
  } else {
    for (int e = base; e < E; ++e) atomicAdd(&deg[ei[E + e]], 1);
  }
}

__global__ void scan_reduce_kernel(const int* __restrict__ deg, int* __restrict__ partial, int n) {
  __shared__ int ws[4];
  int i = blockIdx.x * 256 + threadIdx.x;
  int v = (i < n) ? deg[i] + 1 : 0;
  int lane = threadIdx.x & 63, w = threadIdx.x >> 6;
#pragma unroll
  for (int s = 32; s; s >>= 1) v += __shfl_down(v, s, 64);
  if (lane == 0) ws[w] = v;
  __syncthreads();
  if (threadIdx.x == 0) partial[blockIdx.x] = ws[0] + ws[1] + ws[2] + ws[3];
}

__global__ void scan_partials_kernel(int* __restrict__ partial, int nb) {
  __shared__ int buf[256];
  int t = threadIdx.x;
  int v = (t < nb) ? partial[t] : 0;
  buf[t] = v;
  __syncthreads();
  for (int s = 1; s < 256; s <<= 1) {
    int x = (t >= s) ? buf[t - s] : 0;
    __syncthreads();
    buf[t] += x;
    __syncthreads();
  }
  if (t < nb) partial[t] = buf[t] - v;  // exclusive
}

__global__ void scan_final_kernel(const int* __restrict__ deg, const int* __restrict__ partial,
                                  int* __restrict__ off, int n) {
  __shared__ int ws[4];
  int b = blockIdx.x, t = threadIdx.x;
  int i = b * 256 + t;
  int v = (i < n) ? deg[i] + 1 : 0;
  int lane = t & 63, w = t >> 6;
  int x = v;
#pragma unroll
  for (int s = 1; s < 64; s <<= 1) {
    int tt = __shfl_up(x, s, 64);
    if (lane >= s) x += tt;
  }
  if (lane == 63) ws[w] = x;
  __syncthreads();
  int wo = 0;
  for (int k = 0; k < w; ++k) wo += ws[k];
  int base = partial[b];
  if (i < n) off[i] = base + wo + x - v;
  if (i == n - 1) off[n] = base + wo + x;
}

__global__ void scatter_kernel(const int* __restrict__ ei, int E, const int* __restrict__ off,
                               int* __restrict__ cursor, int* __restrict__ csr_src) {
  int e = blockIdx.x * blockDim.x + threadIdx.x;
  if (e >= E) return;
  int s = ei[e], d = ei[E + e];
  int p = atomicAdd(&cursor[d], 1);
  csr_src[off[d] + p] = s;
}

__global__ void selfloop_kernel(const int* __restrict__ off, int* __restrict__ csr_src, int n) {
  int d = blockIdx.x * blockDim.x + threadIdx.x;
  if (d < n) csr_src[off[d + 1] - 1] = d;
}

// ---------- layer-1 aggregation in EMBEDDING space, 4 edges in flight ----------
// wave = 4 groups of 16 lanes; group g processes edge beg+it*4+g; lane p covers chans p*4..p*4+3
__global__ __launch_bounds__(128) void agg_emb_kernel(
    const int* __restrict__ off, const int* __restrict__ csr_src,
    const __bf16* __restrict__ embb, const float* __restrict__ as_,
    const float* __restrict__ ad_, __bf16* __restrict__ aggE) {
  int d = blockIdx.x * 2 + (threadIdx.x >> 6);
  int lane = threadIdx.x & 63;
  int g = lane >> 4, p = lane & 15;
  float4 adv = *(const float4*)(ad_ + (size_t)d * 4);
  float acc[4][4] = {};   // [head][chan]
  float wsum[4] = {};
  int beg = off[d], end = off[d + 1];
  for (int i0 = beg; i0 < end; i0 += 4) {
    int i = i0 + g;
    float vm = (i < end) ? 1.f : 0.f;
    int idx = (i < end) ? i : (end - 1);
    int s = csr_src[idx];
    float4 asv = *(const float4*)(as_ + (size_t)s * 4);
    float l0 = asv.x + adv.x; l0 = l0 >= 0.f ? l0 : NEG_SLOPE * l0;
    float l1 = asv.y + adv.y; l1 = l1 >= 0.f ? l1 : NEG_SLOPE * l1;
    float l2 = asv.z + adv.z; l2 = l2 >= 0.f ? l2 : NEG_SLOPE * l2;
    float l3 = asv.w + adv.w; l3 = l3 >= 0.f ? l3 : NEG_SLOPE * l3;
    float w0 = __expf(l0) * vm, w1 = __expf(l1) * vm;
    float w2 = __expf(l2) * vm, w3 = __expf(l3) * vm;
    bf16x4 v = *(const bf16x4*)(embb + (size_t)s * 64 + p * 4);
    float f0 = (float)v[0], f1 = (float)v[1], f2 = (float)v[2], f3 = (float)v[3];
    acc[0][0] += w0 * f0; acc[0][1] += w0 * f1; acc[0][2] += w0 * f2; acc[0][3] += w0 * f3;
    acc[1][0] += w1 * f0; acc[1][1] += w1 * f1; acc[1][2] += w1 * f2; acc[1][3] += w1 * f3;
    acc[2][0] += w2 * f0; acc[2][1] += w2 * f1; acc[2][2] += w2 * f2; acc[2][3] += w2 * f3;
    acc[3][0] += w3 * f0; acc[3][1] += w3 * f1; acc[3][2] += w3 * f2; acc[3][3] += w3 * f3;
    wsum[0] += w0; wsum[1] += w1; wsum[2] += w2; wsum[3] += w3;
  }
  // reduce across the 4 groups (lane bits 4,5)
#pragma unroll
  for (int h = 0; h < 4; ++h) {
#pragma unroll
    for (int c = 0; c < 4; ++c) {
      acc[h][c] += __shfl_xor(acc[h][c], 16, 64);
      acc[h][c] += __shfl_xor(acc[h][c], 32, 64);
    }
    wsum[h] += __shfl_xor(wsum[h], 16, 64);
    wsum[h] += __shfl_xor(wsum[h], 32, 64);
  }
  if (g == 0) {
#pragma unroll
    for (int h = 0; h < 4; ++h) {
      float inv = 1.0f / wsum[h];
      bf16x4 o;
      o[0] = (__bf16)(acc[h][0] * inv); o[1] = (__bf16)(acc[h][1] * inv);
      o[2] = (__bf16)(acc[h][2] * inv); o[3] = (__bf16)(acc[h][3] * inv);
      *(bf16x4*)(aggE + (size_t)d * 256 + h * 64 + p * 4) = o;
    }
  }
}

// ---------- reconstruct x1 (per-head MFMA GEMM + bias + ELU) with fused alpha2 partials ----------
// grid.z = head h; writes x1[:, h*128+*] and per-(h, wn-half) alpha2 partial slabs (non-atomic)
__global__ __launch_bounds__(256) void gemm1p_kernel(const __bf16* __restrict__ aggE,
                                                     const __bf16* __restrict__ W1T,
                                                     const float* __restrict__ b1,
                                                     const float* __restrict__ vs2,
                                                     const float* __restrict__ vd2,
                                                     __bf16* __restrict__ x1,
                                                     float* __restrict__ as2p,
                                                     float* __restrict__ ad2p, int M) {
  __shared__ __bf16 Asl[128 * 72];
  __shared__ __bf16 Bsl[128 * 72];
  int tid = threadIdx.x;
  int h = blockIdx.z;
  int m0 = blockIdx.x * 128;
  int wave = tid >> 6, lane = tid & 63;
  int wm = (wave >> 1) * 64, wn = (wave & 1) * 64;
  int l15 = lane & 15, kg = lane >> 4;
#pragma unroll
  for (int i = 0; i < 4; ++i) {
    int c = tid + i * 256;
    int row = c >> 3, off = (c & 7) * 8;
    bf16x8 va = {};
    int gr = m0 + row;
    if (gr < M) va = *(const bf16x8*)(aggE + (size_t)gr * 256 + h * 64 + off);
    *(bf16x8*)(&Asl[row * 72 + off]) = va;
    bf16x8 vb = *(const bf16x8*)(W1T + ((size_t)h * 128 + row) * 64 + off);
    *(bf16x8*)(&Bsl[row * 72 + off]) = vb;
  }
  __syncthreads();
  f32x4 acc[4][4] = {};
#pragma unroll
  for (int ks = 0; ks < 2; ++ks) {
    bf16x8 af[4], bfr[4];
#pragma unroll
    for (int f = 0; f < 4; ++f) {
      af[f]  = *(const bf16x8*)(&Asl[(wm + f * 16 + l15) * 72 + kg * 8 + ks * 32]);
      bfr[f] = *(const bf16x8*)(&Bsl[(wn + f * 16 + l15) * 72 + kg * 8 + ks * 32]);
    }
#pragma unroll
    for (int i = 0; i < 4; ++i)
#pragma unroll
      for (int j = 0; j < 4; ++j)
        acc[i][j] = __builtin_amdgcn_mfma_f32_16x16x32_bf16(af[i], bfr[j], acc[i][j], 0, 0, 0);
  }
  // per-thread column constants
  float bv[4], vsv[4], vdv[4];
#pragma unroll
  for (int j = 0; j < 4; ++j) {
    int col = h * 128 + wn + j * 16 + l15;
    bv[j] = b1[col]; vsv[j] = vs2[col]; vdv[j] = vd2[col];
  }
  int slab = h * 2 + (wn >> 6);
#pragma unroll
  for (int i = 0; i < 4; ++i)
#pragma unroll
    for (int r = 0; r < 4; ++r) {
      int lrow = wm + i * 16 + kg * 4 + r;
      int row = m0 + lrow;
      bool vrow = row < M;
      float ps = 0.f, pd = 0.f;
#pragma unroll
      for (int j = 0; j < 4; ++j) {
        float a = acc[i][j][r] + bv[j];
        a = a > 0.f ? a : __expf(a) - 1.f;   // ELU
        __bf16 xb = (__bf16)a;
        if (vrow) x1[(size_t)row * 512 + h * 128 + wn + j * 16 + l15] = xb;
        float af = (float)xb;
        ps += af * vsv[j];
        pd += af * vdv[j];
      }
      ps += __shfl_xor(ps, 1, 16); ps += __shfl_xor(ps, 2, 16);
      ps += __shfl_xor(ps, 4, 16); ps += __shfl_xor(ps, 8, 16);
      pd += __shfl_xor(pd, 1, 16); pd += __shfl_xor(pd, 2, 16);
      pd += __shfl_xor(pd, 4, 16); pd += __shfl_xor(pd, 8, 16);
      if (l15 == 0 && vrow) {
        as2p[(size_t)slab * M + row] = ps;
        ad2p[(size_t)slab * M + row] = pd;
      }
    }
}

// ---------- merge alpha2 partial slabs ----------
__global__ void merge_alpha2_kernel(const float* __restrict__ as2p, const float* __restrict__ ad2p,
                                    float* __restrict__ as2, float* __restrict__ ad2, int n) {
  int i = blockIdx.x * blockDim.x + threadIdx.x;
  if (i >= n) return;
  float s = 0.f, d = 0.f;
#pragma unroll
  for (int b = 0; b < 8; ++b) {
    s += as2p[(size_t)b * n + i];
    d += ad2p[(size_t)b * n + i];
  }
  as2[i] = s; ad2[i] = d;
}

// ---------- layer-2: per-dst denom + gamma scatter (16-lane group per dst) ----------
__global__ __launch_bounds__(256) void gamma_kernel(
    const int* __restrict__ off, const int* __restrict__ csr_src,
    const float* __restrict__ as2, const float* __restrict__ ad2,
    float* __restrict__ gamma, float invN, int n) {
  int d = (blockIdx.x * 256 + threadIdx.x) >> 4;
  int p = threadIdx.x & 15;
  if (d >= n) return;
  float adv = ad2[d];
  int beg = off[d], end = off[d + 1];
  float wsum = 0.f;
  for (int i = beg + p; i < end; i += 16) {
    float l = as2[csr_src[i]] + adv;
    l = l >= 0.f ? l : NEG_SLOPE * l;
    wsum += __expf(l);
  }
  wsum += __shfl_xor(wsum, 1, 16); wsum += __shfl_xor(wsum, 2, 16);
  wsum += __shfl_xor(wsum, 4, 16); wsum += __shfl_xor(wsum, 8, 16);
  float scale = invN / wsum;
  for (int i = beg + p; i < end; i += 16) {
    int s = csr_src[i];
    float l = as2[s] + adv;
    l = l >= 0.f ? l : NEG_SLOPE * l;
    atomicAdd(&gamma[s], __expf(l) * scale);
  }
}

// ---------- weighted column sum: colsum[c] = sum_r gamma[r] * x1[r,c] ----------
__global__ __launch_bounds__(256) void colsum_kernel(const __bf16* __restrict__ x1,
                                                     const float* __restrict__ gamma,
                                                     float* __restrict__ colsum, int n) {
  int c = threadIdx.x;  // 256
  float a0 = 0.f, a1 = 0.f;
  for (int r = blockIdx.x; r < n; r += gridDim.x) {
    float g = gamma[r];
    a0 += g * (float)x1[(size_t)r * 512 + c];
    a1 += g * (float)x1[(size_t)r * 512 + 256 + c];
  }
  atomicAdd(&colsum[c], a0);
  atomicAdd(&colsum[c + 256], a1);
}

// ---------- final matvec: out[c] = colsum . W2[:,c] + b2[c] ----------
__global__ void final_kernel(const float* __restrict__ colsum, const float* __restrict__ W2,
                             const float* __restrict__ b2, float* __restrict__ out) {
  int c = threadIdx.x;  // 256
  int k0 = blockIdx.x * 64;  // 8 blocks x 64 k
  float acc = 0.f;
  for (int k = k0; k < k0 + 64; ++k) acc += colsum[k] * W2[(size_t)k * 256 + c];
  if (blockIdx.x == 0) acc += b2[c];
  atomicAdd(&out[c], acc);
}

__global__ void bcast_kernel(float* __restrict__ dout, int total) {
  int i = blockIdx.x * blockDim.x + threadIdx.x;
  if (i >= 256 && i < total) dout[i] = dout[i & 255];
}

// ---------- host ----------
extern "C" void kernel_launch(void* const* d_in, const int* in_sizes, int n_in,
                              void* d_out, int out_size, void* d_ws, size_t ws_size,
                              hipStream_t stream) {
  const int* ei = (const int*)d_in[0];
  const float* emb = (const float*)d_in[1];
  const float* W1 = (const float*)d_in[2];
  const float* as1w = (const float*)d_in[3];
  const float* ad1w = (const float*)d_in[4];
  const float* b1 = (const float*)d_in[5];
  const float* W2 = (const float*)d_in[6];
  const float* as2w = (const float*)d_in[7];
  const float* ad2w = (const float*)d_in[8];
  const float* b2 = (const float*)d_in[9];
  float* out = (float*)d_out;

  const int E = in_sizes[0] / 2;
  const int N = in_sizes[1] / 64;
  const int NT = E + N;

  char* ws = (char*)d_ws;
  size_t o = 0;
  auto alloc = [&](size_t bytes) { size_t r = o; o += (bytes + 255) & ~(size_t)255; return r; };
  __bf16* embb  = (__bf16*)(ws + alloc((size_t)N * 64 * 2));
  __bf16* aggE  = (__bf16*)(ws + alloc((size_t)N * 256 * 2));
  __bf16* x1    = (__bf16*)(ws + alloc((size_t)N * 512 * 2));
  __bf16* W1T   = (__bf16*)(ws + alloc((size_t)512 * 64 * 2));
  float* as1    = (float*)(ws + alloc((size_t)N * 4 * 4));
  float* ad1    = (float*)(ws + alloc((size_t)N * 4 * 4));
  float* as2    = (float*)(ws + alloc((size_t)N * 4));
  float* ad2    = (float*)(ws + alloc((size_t)N * 4));
  float* as2p   = (float*)(ws + alloc((size_t)8 * N * 4));
  float* ad2p   = (float*)(ws + alloc((size_t)8 * N * 4));
  size_t zbeg = o;
  int* deg      = (int*)(ws + alloc((size_t)N * 4));
  int* cursor   = (int*)(ws + alloc((size_t)N * 4));
  float* gamma  = (float*)(ws + alloc((size_t)N * 4));
  float* colsum = (float*)(ws + alloc(512 * 4));
  size_t zend = o;
  int* off      = (int*)(ws + alloc((size_t)(N + 1) * 4));
  int* partial  = (int*)(ws + alloc(256 * 4));
  int* csr_src  = (int*)(ws + alloc((size_t)NT * 4));
  float* Vs1    = (float*)(ws + alloc(64 * 4 * 4));
  float* Vd1    = (float*)(ws + alloc(64 * 4 * 4));
  float* vs2    = (float*)(ws + alloc(512 * 4));
  float* vd2    = (float*)(ws + alloc(512 * 4));

  hipMemsetAsync(ws + zbeg, 0, zend - zbeg, stream);
  hipMemsetAsync(d_out, 0, (size_t)out_size * 4, stream);

  // prep
  prep_v1_kernel<<<1, 256, 0, stream>>>(W1, as1w, ad1w, Vs1, Vd1);
  prep_v2_kernel<<<1, 512, 0, stream>>>(W2, as2w, ad2w, vs2, vd2);
  transpose_bf16_kernel<<<(64 * 512 + 255) / 256, 256, 0, stream>>>(W1, W1T, 64, 512);
  int nb = (N + 255) / 256;
  emb_prep_kernel<<<nb, 256, 0, stream>>>(emb, Vs1, Vd1, embb, as1, ad1, N);

  // CSR build
  deg_kernel<<<(E / 4 + 255) / 256, 256, 0, stream>>>(ei, E, deg);
  scan_reduce_kernel<<<nb, 256, 0, stream>>>(deg, partial, N);
  scan_partials_kernel<<<1, 256, 0, stream>>>(partial, nb);
  scan_final_kernel<<<nb, 256, 0, stream>>>(deg, partial, off, N);
  scatter_kernel<<<(E + 255) / 256, 256, 0, stream>>>(ei, E, off, cursor, csr_src);
  selfloop_kernel<<<nb, 256, 0, stream>>>(off, csr_src, N);

  // layer 1: aggregate in emb space, then reconstruct + fused alpha2 partials
  agg_emb_kernel<<<N / 2, 128, 0, stream>>>(off, csr_src, embb, as1, ad1, aggE);
  dim3 g1((N + 127) / 128, 1, 4);
  gemm1p_kernel<<<g1, 256, 0, stream>>>(aggE, W1T, b1, vs2, vd2, x1, as2p, ad2p, N);
  merge_alpha2_kernel<<<nb, 256, 0, stream>>>(as2p, ad2p, as2, ad2, N);

  // layer 2 collapsed: denom+gamma (group-per-dst) -> weighted colsum -> matvec
  gamma_kernel<<<(N * 16 + 255) / 256, 256, 0, stream>>>(off, csr_src, as2, ad2, gamma,
                                                         1.0f / (float)N, N);
  colsum_kernel<<<256, 256, 0, stream>>>(x1, gamma, colsum, N);
  final_kernel<<<8, 256, 0, stream>>>(colsum, W2, b2, out);

  if (out_size > 256) {
    bcast_kernel<<<(out_size + 255) / 256, 256, 0, stream>>>(out, out_size);
  }
}